// Round 1
// 239.023 us; speedup vs baseline: 1.5884x; 1.5884x over previous
//
#include <hip/hip_runtime.h>
#include <hip/hip_bf16.h>

// h_out[v] = sum over edges (u->v) of features[u]
// Counting-sort edges by 32-node bucket; one block per bucket does an
// in-LDS counting sort by local node (ONE rank-returning LDS atomic per
// edge), then 8 threads per node accumulate bf16-packed rows in REGISTERS
// (no ds_add_f32 at all), shfl-reduce, store exclusively.
// bdata is written with PLAIN stores (L2 write-combining; re-read by k6).

#define NN     100000
#define FD     5
#define NOUTT  (NN * FD)      // 500000
#define NPS    32             // nodes per bucket
#define NPS_SH 5
#define NB     3125           // 100000 / 32 exactly
#define NSB    512            // scatter/hist blocks (chunk = 12500 edges)
#define BLK    256

typedef int vint4 __attribute__((ext_vector_type(4)));   // nontemporal-friendly

__device__ inline unsigned bf16rtn(float x) {          // fp32 -> bf16 (RTN)
    unsigned u = __float_as_uint(x);
    u += 0x7fffu + ((u >> 16) & 1u);
    return u >> 16;
}
__device__ inline float lo16(unsigned v) { return __uint_as_float(v << 16); }
__device__ inline float hi16(unsigned v) { return __uint_as_float(v & 0xffff0000u); }

// ---------- K2: per-scatter-block bucket histogram (ushort, [blk][b]) -------
__global__ __launch_bounds__(BLK) void k2_hist(const int* __restrict__ dst,
                                               unsigned short* __restrict__ bh,
                                               int chunk) {
    __shared__ int h[NB];
    for (int b = threadIdx.x; b < NB; b += BLK) h[b] = 0;
    __syncthreads();
    long long e0 = (long long)blockIdx.x * chunk;
    const vint4* d4 = (const vint4*)(dst + e0);
    int n4 = chunk >> 2;
    int i = threadIdx.x;
    for (; i + 3 * BLK < n4; i += 4 * BLK) {
        vint4 d0 = __builtin_nontemporal_load(&d4[i]);
        vint4 d1 = __builtin_nontemporal_load(&d4[i + BLK]);
        vint4 d2 = __builtin_nontemporal_load(&d4[i + 2 * BLK]);
        vint4 d3 = __builtin_nontemporal_load(&d4[i + 3 * BLK]);
        __builtin_amdgcn_sched_barrier(0);
        atomicAdd(&h[d0[0] >> NPS_SH], 1); atomicAdd(&h[d0[1] >> NPS_SH], 1);
        atomicAdd(&h[d0[2] >> NPS_SH], 1); atomicAdd(&h[d0[3] >> NPS_SH], 1);
        atomicAdd(&h[d1[0] >> NPS_SH], 1); atomicAdd(&h[d1[1] >> NPS_SH], 1);
        atomicAdd(&h[d1[2] >> NPS_SH], 1); atomicAdd(&h[d1[3] >> NPS_SH], 1);
        atomicAdd(&h[d2[0] >> NPS_SH], 1); atomicAdd(&h[d2[1] >> NPS_SH], 1);
        atomicAdd(&h[d2[2] >> NPS_SH], 1); atomicAdd(&h[d2[3] >> NPS_SH], 1);
        atomicAdd(&h[d3[0] >> NPS_SH], 1); atomicAdd(&h[d3[1] >> NPS_SH], 1);
        atomicAdd(&h[d3[2] >> NPS_SH], 1); atomicAdd(&h[d3[3] >> NPS_SH], 1);
    }
    for (; i < n4; i += BLK) {
        vint4 d = __builtin_nontemporal_load(&d4[i]);
        atomicAdd(&h[d[0] >> NPS_SH], 1); atomicAdd(&h[d[1] >> NPS_SH], 1);
        atomicAdd(&h[d[2] >> NPS_SH], 1); atomicAdd(&h[d[3] >> NPS_SH], 1);
    }
    __syncthreads();
    unsigned short* row = bh + (size_t)blockIdx.x * NB;
    for (int b = threadIdx.x; b < NB; b += BLK) row[b] = (unsigned short)h[b];
}

// ---------- K3: per bucket, exclusive scan across the NSB blocks ------------
__global__ __launch_bounds__(BLK) void k3_scanblk(unsigned short* __restrict__ bh,
                                                  int* __restrict__ btot) {
    __shared__ int s[BLK];
    int b = blockIdx.x, t = threadIdx.x;
    int v0 = bh[(size_t)(2 * t)     * NB + b];
    int v1 = bh[(size_t)(2 * t + 1) * NB + b];
    int pair = v0 + v1;
    s[t] = pair;
    __syncthreads();
    for (int off = 1; off < BLK; off <<= 1) {
        int v = (t >= off) ? s[t - off] : 0;
        __syncthreads();
        s[t] += v;
        __syncthreads();
    }
    int base = s[t] - pair;  // exclusive over pairs
    bh[(size_t)(2 * t)     * NB + b] = (unsigned short)base;
    bh[(size_t)(2 * t + 1) * NB + b] = (unsigned short)(base + v0);
    if (t == BLK - 1) btot[b] = s[t];
}

// ---------- K4: exclusive scan of bucket totals (1 block) -------------------
#define VPT 13   // 13*256 = 3328 >= 3125
__global__ __launch_bounds__(BLK) void k4_scanbkt(const int* __restrict__ btot,
                                                  int* __restrict__ bbase) {
    __shared__ int s[BLK];
    int t = threadIdx.x;
    int v[VPT], sum = 0;
#pragma unroll
    for (int k = 0; k < VPT; ++k) {
        int i = VPT * t + k;
        v[k] = (i < NB) ? btot[i] : 0;
        sum += v[k];
    }
    s[t] = sum;
    __syncthreads();
    for (int off = 1; off < BLK; off <<= 1) {
        int u = (t >= off) ? s[t - off] : 0;
        __syncthreads();
        s[t] += u;
        __syncthreads();
    }
    int run = s[t] - sum;
#pragma unroll
    for (int k = 0; k < VPT; ++k) {
        int i = VPT * t + k;
        if (i < NB) bbase[i] = run;
        run += v[k];
    }
}

// ---------- K5: scatter packed (u<<5 | local_dst) into sorted order ---------
__global__ __launch_bounds__(BLK) void k5_scatter(const int* __restrict__ src,
                                                  const int* __restrict__ dst,
                                                  const unsigned short* __restrict__ bh,
                                                  const int* __restrict__ bbase,
                                                  int* __restrict__ bdata, int chunk) {
    __shared__ int cur[NB];
    int blk = blockIdx.x;
    const unsigned short* row = bh + (size_t)blk * NB;
    for (int b = threadIdx.x; b < NB; b += BLK)
        cur[b] = bbase[b] + (int)row[b];
    __syncthreads();
    long long e0 = (long long)blk * chunk;
    const vint4* d4 = (const vint4*)(dst + e0);
    const vint4* s4 = (const vint4*)(src + e0);
    int n4 = chunk >> 2;
    int i = threadIdx.x;
    for (; i + 3 * BLK < n4; i += 4 * BLK) {
        vint4 d[4], s[4];
#pragma unroll
        for (int k = 0; k < 4; ++k) {
            d[k] = __builtin_nontemporal_load(&d4[i + k * BLK]);
            s[k] = __builtin_nontemporal_load(&s4[i + k * BLK]);
        }
        __builtin_amdgcn_sched_barrier(0);
#pragma unroll
        for (int k = 0; k < 4; ++k) {
#pragma unroll
            for (int j = 0; j < 4; ++j) {
                int vv = d[k][j];
                int uu = s[k][j];
                int b = vv >> NPS_SH;
                int off = atomicAdd(&cur[b], 1);
                bdata[off] = (uu << NPS_SH) | (vv & (NPS - 1));  // PLAIN store
            }
        }
    }
    for (; i < n4; i += BLK) {
        vint4 d = __builtin_nontemporal_load(&d4[i]);
        vint4 s = __builtin_nontemporal_load(&s4[i]);
#pragma unroll
        for (int j = 0; j < 4; ++j) {
            int vv = d[j];
            int uu = s[j];
            int b = vv >> NPS_SH;
            int off = atomicAdd(&cur[b], 1);
            bdata[off] = (uu << NPS_SH) | (vv & (NPS - 1));      // PLAIN store
        }
    }
}

// ---------- K1: bf16-pack rows 5 f32 -> 16 B (after k5: overlaps bhist) -----
__global__ __launch_bounds__(BLK) void k1_pad(const float* __restrict__ f,
                                              uint4* __restrict__ fp) {
    int i = blockIdx.x * BLK + threadIdx.x;
    if (i < NN) {
        const float* r = f + (long long)i * FD;
        unsigned w0 = bf16rtn(r[0]), w1 = bf16rtn(r[1]), w2 = bf16rtn(r[2]);
        unsigned w3 = bf16rtn(r[3]), w4 = bf16rtn(r[4]);
        uint4 o;
        o.x = w0 | (w1 << 16);
        o.y = w2 | (w3 << 16);
        o.z = w4;
        o.w = 0u;
        fp[i] = o;
    }
}

// ---------- K6: one block per bucket — in-LDS counting sort by local node,
//              then register accumulation (8 threads per node), shfl reduce.
//              Exactly ONE LDS atomic per edge (rank-returning histogram).
#define CAP 4096              // chunk capacity (bucket mean 2048, max ~2.3K)
#define WPT (CAP / BLK)       // 16 packed words per thread per chunk
__global__ __launch_bounds__(BLK) void k6_gather(const int* __restrict__ bdata,
                                                 const uint4* __restrict__ fp,
                                                 const int* __restrict__ bbase,
                                                 const int* __restrict__ btot,
                                                 float* __restrict__ out) {
    __shared__ int seg[CAP];      // u's sorted by local node (16 KB)
    __shared__ int hist[NPS];     // per-node counts
    __shared__ int sbase[NPS];    // per-node segment starts
    int t = threadIdx.x;
    int b = blockIdx.x;
    int base = bbase[b];
    int n = btot[b];

    int grp = t >> 3;             // node 0..31 this 8-thread team owns
    int sub = t & 7;
    float a0 = 0.f, a1 = 0.f, a2 = 0.f, a3 = 0.f, a4 = 0.f;

    for (int c0 = 0; c0 < n; c0 += CAP) {
        int m = n - c0; if (m > CAP) m = CAP;
        if (t < NPS) hist[t] = 0;
        __syncthreads();

        // Pass 1: load packed words; rank-returning histogram (the ONLY atomic).
        int w[WPT], r[WPT];
#pragma unroll
        for (int k = 0; k < WPT; ++k) {
            int idx = t + k * BLK;
            w[k] = (idx < m) ? bdata[base + c0 + idx] : -1;  // packed word >= 0 always
        }
#pragma unroll
        for (int k = 0; k < WPT; ++k)
            r[k] = (w[k] >= 0) ? atomicAdd(&hist[w[k] & (NPS - 1)], 1) : 0;
        __syncthreads();

        // Exclusive scan of 32 counts (wave 0, lanes 0..31).
        if (t < NPS) {
            int v = hist[t];
            int s = v;
#pragma unroll
            for (int off = 1; off < NPS; off <<= 1) {
                int u = __shfl_up(s, off, 64);
                if (t >= off) s += u;
            }
            sbase[t] = s - v;
        }
        __syncthreads();

        // Pass 2: scatter u into sorted position (no atomics — rank is known).
#pragma unroll
        for (int k = 0; k < WPT; ++k) {
            if (w[k] >= 0)
                seg[sbase[w[k] & (NPS - 1)] + r[k]] = w[k] >> NPS_SH;
        }
        __syncthreads();

        // Accumulate: 8 threads per node, strided slice, registers only.
        int s0 = sbase[grp], cnt = hist[grp];
        int j = sub;
        for (; j + 24 < cnt; j += 32) {
            int u0 = seg[s0 + j],      u1 = seg[s0 + j + 8];
            int u2 = seg[s0 + j + 16], u3 = seg[s0 + j + 24];
            uint4 q0 = fp[u0], q1 = fp[u1], q2 = fp[u2], q3 = fp[u3];
            a0 += lo16(q0.x); a1 += hi16(q0.x); a2 += lo16(q0.y); a3 += hi16(q0.y); a4 += lo16(q0.z);
            a0 += lo16(q1.x); a1 += hi16(q1.x); a2 += lo16(q1.y); a3 += hi16(q1.y); a4 += lo16(q1.z);
            a0 += lo16(q2.x); a1 += hi16(q2.x); a2 += lo16(q2.y); a3 += hi16(q2.y); a4 += lo16(q2.z);
            a0 += lo16(q3.x); a1 += hi16(q3.x); a2 += lo16(q3.y); a3 += hi16(q3.y); a4 += lo16(q3.z);
        }
        for (; j < cnt; j += 8) {
            int u = seg[s0 + j];
            uint4 q = fp[u];
            a0 += lo16(q.x); a1 += hi16(q.x); a2 += lo16(q.y); a3 += hi16(q.y); a4 += lo16(q.z);
        }
        __syncthreads();   // LDS reused next chunk
    }

    // Reduce the 8 partials per node within the 8-lane cluster.
    a0 += __shfl_down(a0, 4, 8); a0 += __shfl_down(a0, 2, 8); a0 += __shfl_down(a0, 1, 8);
    a1 += __shfl_down(a1, 4, 8); a1 += __shfl_down(a1, 2, 8); a1 += __shfl_down(a1, 1, 8);
    a2 += __shfl_down(a2, 4, 8); a2 += __shfl_down(a2, 2, 8); a2 += __shfl_down(a2, 1, 8);
    a3 += __shfl_down(a3, 4, 8); a3 += __shfl_down(a3, 2, 8); a3 += __shfl_down(a3, 1, 8);
    a4 += __shfl_down(a4, 4, 8); a4 += __shfl_down(a4, 2, 8); a4 += __shfl_down(a4, 1, 8);
    if (sub == 0) {
        // Exclusive owner; NB*NPS*FD == NOUTT exactly.
        float* o = out + (size_t)b * (NPS * FD) + grp * FD;
        o[0] = a0; o[1] = a1; o[2] = a2; o[3] = a3; o[4] = a4;
    }
}

// ---------- Fallback: direct global atomics ---------------------------------
__global__ void scatter_add_fallback(const float* __restrict__ features,
                                     const int* __restrict__ src,
                                     const int* __restrict__ dst,
                                     float* __restrict__ out, int n_edges) {
    int idx = blockIdx.x * blockDim.x + threadIdx.x;
    int stride = gridDim.x * blockDim.x;
    for (int e = idx; e < n_edges; e += stride) {
        int u = src[e], v = dst[e];
        const float* f = features + (long long)u * FD;
        float* o = out + (long long)v * FD;
#pragma unroll
        for (int k = 0; k < FD; ++k) atomicAdd(&o[k], f[k]);
    }
}

extern "C" void kernel_launch(void* const* d_in, const int* in_sizes, int n_in,
                              void* d_out, int out_size, void* d_ws, size_t ws_size,
                              hipStream_t stream) {
    const float* features = (const float*)d_in[0];
    const int*   src      = (const int*)d_in[1];
    const int*   dst      = (const int*)d_in[2];
    float* out = (float*)d_out;
    int n_edges = in_sizes[1];

    // ws carve. bhist and fpad OVERLAP (bhist dead after k5; k1 runs after k5).
    size_t o_bd = 0;                                       // bdata: E*4
    size_t o_bh = o_bd + (size_t)n_edges * 4;              // bhist: NSB*NB*2 (3.2MB)
    size_t o_fp = o_bh;                                    // fpad:  NN*16   (1.6MB)
    size_t sz_overlap = (size_t)NSB * NB * 2;
    size_t sz_fp = (size_t)NN * sizeof(uint4);
    if (sz_fp > sz_overlap) sz_overlap = sz_fp;
    size_t o_bb = o_bh + ((sz_overlap + 15) & ~(size_t)15);// bucket_base: NB*4
    size_t o_bt = o_bb + (size_t)NB * 4;                   // bucket_total: NB*4
    size_t need = o_bt + (size_t)NB * 4;

    bool fast = (out_size == NOUTT) && (in_sizes[0] == NOUTT) &&
                (n_edges % (NSB * 4) == 0) && (need <= ws_size);

    if (fast) {
        char* w = (char*)d_ws;
        int*            bdata = (int*)(w + o_bd);
        unsigned short* bhist = (unsigned short*)(w + o_bh);
        uint4*          fpad  = (uint4*)(w + o_fp);
        int*            bbase = (int*)(w + o_bb);
        int*            btot  = (int*)(w + o_bt);
        int chunk = n_edges / NSB;
        k2_hist  <<<NSB, BLK, 0, stream>>>(dst, bhist, chunk);
        k3_scanblk<<<NB, BLK, 0, stream>>>(bhist, btot);
        k4_scanbkt<<<1,  BLK, 0, stream>>>(btot, bbase);
        k5_scatter<<<NSB, BLK, 0, stream>>>(src, dst, bhist, bbase, bdata, chunk);
        k1_pad   <<<(NN + BLK - 1) / BLK, BLK, 0, stream>>>(features, fpad);
        k6_gather <<<NB, BLK, 0, stream>>>(bdata, fpad, bbase, btot, out);
    } else {
        (void)hipMemsetAsync(d_out, 0, (size_t)out_size * sizeof(float), stream);
        int grid = (n_edges + BLK - 1) / BLK;
        if (grid > 65535) grid = 65535;
        scatter_add_fallback<<<grid, BLK, 0, stream>>>(features, src, dst, out, n_edges);
    }
}

// Round 2
// 211.718 us; speedup vs baseline: 1.7932x; 1.1290x over previous
//
#include <hip/hip_runtime.h>
#include <hip/hip_bf16.h>

// h_out[v] = sum over edges (u->v) of features[u]
// Counting-sort edges by 32-node bucket; one block per bucket does an
// in-LDS counting sort by local node (ONE rank-returning LDS atomic per
// edge), then 8 threads per node accumulate bf16-packed rows in REGISTERS
// (no ds_add_f32 at all), shfl-reduce, store exclusively.
// bdata is written with PLAIN stores; scatter blocks are XCD-swizzled so
// adjacent bdata sub-ranges share ONE coherent L2 (kills the 6.4x
// write amplification from cross-XCD false sharing of 64B lines).

#define NN     100000
#define FD     5
#define NOUTT  (NN * FD)      // 500000
#define NPS    32             // nodes per bucket
#define NPS_SH 5
#define NB     3125           // 100000 / 32 exactly
#define NSB    512            // scatter/hist blocks (chunk = 12500 edges)
#define BLK    256
#define BLK5   512            // wider blocks for k2/k5 (latency-heavy scatter)
#define NXCD   8

typedef int vint4 __attribute__((ext_vector_type(4)));   // nontemporal-friendly

__device__ inline unsigned bf16rtn(float x) {          // fp32 -> bf16 (RTN)
    unsigned u = __float_as_uint(x);
    u += 0x7fffu + ((u >> 16) & 1u);
    return u >> 16;
}
__device__ inline float lo16(unsigned v) { return __uint_as_float(v << 16); }
__device__ inline float hi16(unsigned v) { return __uint_as_float(v & 0xffff0000u); }

// XCD-contiguous chunk assignment: default dispatch round-robins consecutive
// blockIdx across the 8 XCDs; give each XCD a contiguous range of chunks so
// adjacent sub-ranges inside every bucket region are written from the SAME
// (coherent) L2 and partial 64B lines merge before eviction.
__device__ inline int chunk_of_block(int bid) {
    return (bid & (NXCD - 1)) * (NSB / NXCD) + (bid >> 3);
}

// ---------- K2: per-scatter-block bucket histogram (ushort, [chunk][b]) -----
__global__ __launch_bounds__(BLK5) void k2_hist(const int* __restrict__ dst,
                                                unsigned short* __restrict__ bh,
                                                int chunk) {
    __shared__ int h[NB];
    for (int b = threadIdx.x; b < NB; b += BLK5) h[b] = 0;
    __syncthreads();
    int cblk = chunk_of_block(blockIdx.x);
    long long e0 = (long long)cblk * chunk;
    const vint4* d4 = (const vint4*)(dst + e0);
    int n4 = chunk >> 2;
    int i = threadIdx.x;
    for (; i + 3 * BLK5 < n4; i += 4 * BLK5) {
        vint4 d0 = __builtin_nontemporal_load(&d4[i]);
        vint4 d1 = __builtin_nontemporal_load(&d4[i + BLK5]);
        vint4 d2 = __builtin_nontemporal_load(&d4[i + 2 * BLK5]);
        vint4 d3 = __builtin_nontemporal_load(&d4[i + 3 * BLK5]);
        __builtin_amdgcn_sched_barrier(0);
        atomicAdd(&h[d0[0] >> NPS_SH], 1); atomicAdd(&h[d0[1] >> NPS_SH], 1);
        atomicAdd(&h[d0[2] >> NPS_SH], 1); atomicAdd(&h[d0[3] >> NPS_SH], 1);
        atomicAdd(&h[d1[0] >> NPS_SH], 1); atomicAdd(&h[d1[1] >> NPS_SH], 1);
        atomicAdd(&h[d1[2] >> NPS_SH], 1); atomicAdd(&h[d1[3] >> NPS_SH], 1);
        atomicAdd(&h[d2[0] >> NPS_SH], 1); atomicAdd(&h[d2[1] >> NPS_SH], 1);
        atomicAdd(&h[d2[2] >> NPS_SH], 1); atomicAdd(&h[d2[3] >> NPS_SH], 1);
        atomicAdd(&h[d3[0] >> NPS_SH], 1); atomicAdd(&h[d3[1] >> NPS_SH], 1);
        atomicAdd(&h[d3[2] >> NPS_SH], 1); atomicAdd(&h[d3[3] >> NPS_SH], 1);
    }
    for (; i < n4; i += BLK5) {
        vint4 d = __builtin_nontemporal_load(&d4[i]);
        atomicAdd(&h[d[0] >> NPS_SH], 1); atomicAdd(&h[d[1] >> NPS_SH], 1);
        atomicAdd(&h[d[2] >> NPS_SH], 1); atomicAdd(&h[d[3] >> NPS_SH], 1);
    }
    __syncthreads();
    unsigned short* row = bh + (size_t)cblk * NB;
    for (int b = threadIdx.x; b < NB; b += BLK5) row[b] = (unsigned short)h[b];
}

// ---------- K3: per bucket, exclusive scan across the NSB chunks ------------
__global__ __launch_bounds__(BLK) void k3_scanblk(unsigned short* __restrict__ bh,
                                                  int* __restrict__ btot) {
    __shared__ int s[BLK];
    int b = blockIdx.x, t = threadIdx.x;
    int v0 = bh[(size_t)(2 * t)     * NB + b];
    int v1 = bh[(size_t)(2 * t + 1) * NB + b];
    int pair = v0 + v1;
    s[t] = pair;
    __syncthreads();
    for (int off = 1; off < BLK; off <<= 1) {
        int v = (t >= off) ? s[t - off] : 0;
        __syncthreads();
        s[t] += v;
        __syncthreads();
    }
    int base = s[t] - pair;  // exclusive over pairs
    bh[(size_t)(2 * t)     * NB + b] = (unsigned short)base;
    bh[(size_t)(2 * t + 1) * NB + b] = (unsigned short)(base + v0);
    if (t == BLK - 1) btot[b] = s[t];
}

// ---------- K4: exclusive scan of bucket totals (1 block) -------------------
#define VPT 13   // 13*256 = 3328 >= 3125
__global__ __launch_bounds__(BLK) void k4_scanbkt(const int* __restrict__ btot,
                                                  int* __restrict__ bbase) {
    __shared__ int s[BLK];
    int t = threadIdx.x;
    int v[VPT], sum = 0;
#pragma unroll
    for (int k = 0; k < VPT; ++k) {
        int i = VPT * t + k;
        v[k] = (i < NB) ? btot[i] : 0;
        sum += v[k];
    }
    s[t] = sum;
    __syncthreads();
    for (int off = 1; off < BLK; off <<= 1) {
        int u = (t >= off) ? s[t - off] : 0;
        __syncthreads();
        s[t] += u;
        __syncthreads();
    }
    int run = s[t] - sum;
#pragma unroll
    for (int k = 0; k < VPT; ++k) {
        int i = VPT * t + k;
        if (i < NB) bbase[i] = run;
        run += v[k];
    }
}

// ---------- K5: scatter packed (u<<5 | local_dst) into sorted order ---------
__global__ __launch_bounds__(BLK5) void k5_scatter(const int* __restrict__ src,
                                                   const int* __restrict__ dst,
                                                   const unsigned short* __restrict__ bh,
                                                   const int* __restrict__ bbase,
                                                   int* __restrict__ bdata, int chunk) {
    __shared__ int cur[NB];
    int cblk = chunk_of_block(blockIdx.x);
    const unsigned short* row = bh + (size_t)cblk * NB;
    for (int b = threadIdx.x; b < NB; b += BLK5)
        cur[b] = bbase[b] + (int)row[b];
    __syncthreads();
    long long e0 = (long long)cblk * chunk;
    const vint4* d4 = (const vint4*)(dst + e0);
    const vint4* s4 = (const vint4*)(src + e0);
    int n4 = chunk >> 2;
    int i = threadIdx.x;
    for (; i + 3 * BLK5 < n4; i += 4 * BLK5) {
        vint4 d[4], s[4];
#pragma unroll
        for (int k = 0; k < 4; ++k) {
            d[k] = __builtin_nontemporal_load(&d4[i + k * BLK5]);
            s[k] = __builtin_nontemporal_load(&s4[i + k * BLK5]);
        }
        __builtin_amdgcn_sched_barrier(0);
#pragma unroll
        for (int k = 0; k < 4; ++k) {
#pragma unroll
            for (int j = 0; j < 4; ++j) {
                int vv = d[k][j];
                int uu = s[k][j];
                int b = vv >> NPS_SH;
                int off = atomicAdd(&cur[b], 1);
                bdata[off] = (uu << NPS_SH) | (vv & (NPS - 1));  // PLAIN store
            }
        }
    }
    for (; i < n4; i += BLK5) {
        vint4 d = __builtin_nontemporal_load(&d4[i]);
        vint4 s = __builtin_nontemporal_load(&s4[i]);
#pragma unroll
        for (int j = 0; j < 4; ++j) {
            int vv = d[j];
            int uu = s[j];
            int b = vv >> NPS_SH;
            int off = atomicAdd(&cur[b], 1);
            bdata[off] = (uu << NPS_SH) | (vv & (NPS - 1));      // PLAIN store
        }
    }
}

// ---------- K1: bf16-pack rows 5 f32 -> 16 B (after k5: overlaps bhist) -----
__global__ __launch_bounds__(BLK) void k1_pad(const float* __restrict__ f,
                                              uint4* __restrict__ fp) {
    int i = blockIdx.x * BLK + threadIdx.x;
    if (i < NN) {
        const float* r = f + (long long)i * FD;
        unsigned w0 = bf16rtn(r[0]), w1 = bf16rtn(r[1]), w2 = bf16rtn(r[2]);
        unsigned w3 = bf16rtn(r[3]), w4 = bf16rtn(r[4]);
        uint4 o;
        o.x = w0 | (w1 << 16);
        o.y = w2 | (w3 << 16);
        o.z = w4;
        o.w = 0u;
        fp[i] = o;
    }
}

// ---------- K6: one block per bucket — in-LDS counting sort by local node,
//              then register accumulation (8 threads per node), shfl reduce.
//              Exactly ONE LDS atomic per edge (rank-returning histogram).
#define CAP 4096              // chunk capacity (bucket mean 2048, max ~2.3K)
#define WPT (CAP / BLK)       // 16 packed words per thread per chunk
__global__ __launch_bounds__(BLK) void k6_gather(const int* __restrict__ bdata,
                                                 const uint4* __restrict__ fp,
                                                 const int* __restrict__ bbase,
                                                 const int* __restrict__ btot,
                                                 float* __restrict__ out) {
    __shared__ int seg[CAP];      // u's sorted by local node (16 KB)
    __shared__ int hist[NPS];     // per-node counts
    __shared__ int sbase[NPS];    // per-node segment starts
    int t = threadIdx.x;
    int b = blockIdx.x;
    int base = bbase[b];
    int n = btot[b];

    int grp = t >> 3;             // node 0..31 this 8-thread team owns
    int sub = t & 7;
    float a0 = 0.f, a1 = 0.f, a2 = 0.f, a3 = 0.f, a4 = 0.f;

    for (int c0 = 0; c0 < n; c0 += CAP) {
        int m = n - c0; if (m > CAP) m = CAP;
        if (t < NPS) hist[t] = 0;
        __syncthreads();

        // Pass 1: load packed words; rank-returning histogram (the ONLY atomic).
        int w[WPT], r[WPT];
#pragma unroll
        for (int k = 0; k < WPT; ++k) {
            int idx = t + k * BLK;
            w[k] = (idx < m) ? bdata[base + c0 + idx] : -1;  // packed word >= 0 always
        }
#pragma unroll
        for (int k = 0; k < WPT; ++k)
            r[k] = (w[k] >= 0) ? atomicAdd(&hist[w[k] & (NPS - 1)], 1) : 0;
        __syncthreads();

        // Exclusive scan of 32 counts (wave 0, lanes 0..31).
        if (t < NPS) {
            int v = hist[t];
            int s = v;
#pragma unroll
            for (int off = 1; off < NPS; off <<= 1) {
                int u = __shfl_up(s, off, 64);
                if (t >= off) s += u;
            }
            sbase[t] = s - v;
        }
        __syncthreads();

        // Pass 2: scatter u into sorted position (no atomics — rank is known).
#pragma unroll
        for (int k = 0; k < WPT; ++k) {
            if (w[k] >= 0)
                seg[sbase[w[k] & (NPS - 1)] + r[k]] = w[k] >> NPS_SH;
        }
        __syncthreads();

        // Accumulate: 8 threads per node, strided slice, registers only.
        int s0 = sbase[grp], cnt = hist[grp];
        int j = sub;
        for (; j + 24 < cnt; j += 32) {
            int u0 = seg[s0 + j],      u1 = seg[s0 + j + 8];
            int u2 = seg[s0 + j + 16], u3 = seg[s0 + j + 24];
            uint4 q0 = fp[u0], q1 = fp[u1], q2 = fp[u2], q3 = fp[u3];
            a0 += lo16(q0.x); a1 += hi16(q0.x); a2 += lo16(q0.y); a3 += hi16(q0.y); a4 += lo16(q0.z);
            a0 += lo16(q1.x); a1 += hi16(q1.x); a2 += lo16(q1.y); a3 += hi16(q1.y); a4 += lo16(q1.z);
            a0 += lo16(q2.x); a1 += hi16(q2.x); a2 += lo16(q2.y); a3 += hi16(q2.y); a4 += lo16(q2.z);
            a0 += lo16(q3.x); a1 += hi16(q3.x); a2 += lo16(q3.y); a3 += hi16(q3.y); a4 += lo16(q3.z);
        }
        for (; j < cnt; j += 8) {
            int u = seg[s0 + j];
            uint4 q = fp[u];
            a0 += lo16(q.x); a1 += hi16(q.x); a2 += lo16(q.y); a3 += hi16(q.y); a4 += lo16(q.z);
        }
        __syncthreads();   // LDS reused next chunk
    }

    // Reduce the 8 partials per node within the 8-lane cluster.
    a0 += __shfl_down(a0, 4, 8); a0 += __shfl_down(a0, 2, 8); a0 += __shfl_down(a0, 1, 8);
    a1 += __shfl_down(a1, 4, 8); a1 += __shfl_down(a1, 2, 8); a1 += __shfl_down(a1, 1, 8);
    a2 += __shfl_down(a2, 4, 8); a2 += __shfl_down(a2, 2, 8); a2 += __shfl_down(a2, 1, 8);
    a3 += __shfl_down(a3, 4, 8); a3 += __shfl_down(a3, 2, 8); a3 += __shfl_down(a3, 1, 8);
    a4 += __shfl_down(a4, 4, 8); a4 += __shfl_down(a4, 2, 8); a4 += __shfl_down(a4, 1, 8);
    if (sub == 0) {
        // Exclusive owner; NB*NPS*FD == NOUTT exactly.
        float* o = out + (size_t)b * (NPS * FD) + grp * FD;
        o[0] = a0; o[1] = a1; o[2] = a2; o[3] = a3; o[4] = a4;
    }
}

// ---------- Fallback: direct global atomics ---------------------------------
__global__ void scatter_add_fallback(const float* __restrict__ features,
                                     const int* __restrict__ src,
                                     const int* __restrict__ dst,
                                     float* __restrict__ out, int n_edges) {
    int idx = blockIdx.x * blockDim.x + threadIdx.x;
    int stride = gridDim.x * blockDim.x;
    for (int e = idx; e < n_edges; e += stride) {
        int u = src[e], v = dst[e];
        const float* f = features + (long long)u * FD;
        float* o = out + (long long)v * FD;
#pragma unroll
        for (int k = 0; k < FD; ++k) atomicAdd(&o[k], f[k]);
    }
}

extern "C" void kernel_launch(void* const* d_in, const int* in_sizes, int n_in,
                              void* d_out, int out_size, void* d_ws, size_t ws_size,
                              hipStream_t stream) {
    const float* features = (const float*)d_in[0];
    const int*   src      = (const int*)d_in[1];
    const int*   dst      = (const int*)d_in[2];
    float* out = (float*)d_out;
    int n_edges = in_sizes[1];

    // ws carve. bhist and fpad OVERLAP (bhist dead after k5; k1 runs after k5).
    size_t o_bd = 0;                                       // bdata: E*4
    size_t o_bh = o_bd + (size_t)n_edges * 4;              // bhist: NSB*NB*2 (3.2MB)
    size_t o_fp = o_bh;                                    // fpad:  NN*16   (1.6MB)
    size_t sz_overlap = (size_t)NSB * NB * 2;
    size_t sz_fp = (size_t)NN * sizeof(uint4);
    if (sz_fp > sz_overlap) sz_overlap = sz_fp;
    size_t o_bb = o_bh + ((sz_overlap + 15) & ~(size_t)15);// bucket_base: NB*4
    size_t o_bt = o_bb + (size_t)NB * 4;                   // bucket_total: NB*4
    size_t need = o_bt + (size_t)NB * 4;

    bool fast = (out_size == NOUTT) && (in_sizes[0] == NOUTT) &&
                (n_edges % (NSB * 4) == 0) && (need <= ws_size);

    if (fast) {
        char* w = (char*)d_ws;
        int*            bdata = (int*)(w + o_bd);
        unsigned short* bhist = (unsigned short*)(w + o_bh);
        uint4*          fpad  = (uint4*)(w + o_fp);
        int*            bbase = (int*)(w + o_bb);
        int*            btot  = (int*)(w + o_bt);
        int chunk = n_edges / NSB;
        k2_hist  <<<NSB, BLK5, 0, stream>>>(dst, bhist, chunk);
        k3_scanblk<<<NB, BLK, 0, stream>>>(bhist, btot);
        k4_scanbkt<<<1,  BLK, 0, stream>>>(btot, bbase);
        k5_scatter<<<NSB, BLK5, 0, stream>>>(src, dst, bhist, bbase, bdata, chunk);
        k1_pad   <<<(NN + BLK - 1) / BLK, BLK, 0, stream>>>(features, fpad);
        k6_gather <<<NB, BLK, 0, stream>>>(bdata, fpad, bbase, btot, out);
    } else {
        (void)hipMemsetAsync(d_out, 0, (size_t)out_size * sizeof(float), stream);
        int grid = (n_edges + BLK - 1) / BLK;
        if (grid > 65535) grid = 65535;
        scatter_add_fallback<<<grid, BLK, 0, stream>>>(features, src, dst, out, n_edges);
    }
}

// Round 3
// 190.191 us; speedup vs baseline: 1.9962x; 1.1132x over previous
//
#include <hip/hip_runtime.h>
#include <hip/hip_bf16.h>

// h_out[v] = sum over edges (u->v) of features[u]
// CHUNK-LOCAL counting sort: each scatter block sorts its own 12500-edge
// chunk by 32-node bucket and writes it to its OWN contiguous bdata region
// (50KB window -> scatter fully absorbed by L2, HBM writes sequential,
// 25.6MB clean instead of 110MB amplified). No cross-chunk scan needed:
// k2 fuses hist+per-chunk-exclusive-scan; k3/k4 deleted.
// k6 (one block per bucket, consecutive buckets on the same XCD) gathers the
// 512 per-chunk sub-ranges (XCD slice of bdata ~3.2MB -> L2-resident),
// rank-sorts in LDS (ONE atomic per edge) and accumulates in registers.

#define NN     100000
#define FD     5
#define NOUTT  (NN * FD)      // 500000
#define NPS    32             // nodes per bucket
#define NPS_SH 5
#define NB     3125           // 100000 / 32 exactly
#define NBP1   3126           // pscan row length (sentinel row[NB] = chunk)
#define NSB    512            // scatter/hist blocks (chunk = 12500 edges)
#define BLK    256
#define BLK5   512            // wide blocks for k2/k5
#define NXCD   8
#define K2VPT  7              // 7*512 = 3584 >= 3125 (k2 tail scan)

typedef int vint4 __attribute__((ext_vector_type(4)));

__device__ inline unsigned bf16rtn(float x) {          // fp32 -> bf16 (RTN)
    unsigned u = __float_as_uint(x);
    u += 0x7fffu + ((u >> 16) & 1u);
    return u >> 16;
}
__device__ inline float lo16(unsigned v) { return __uint_as_float(v << 16); }
__device__ inline float hi16(unsigned v) { return __uint_as_float(v & 0xffff0000u); }

// XCD-contiguous chunk assignment for k2/k5 (512 = 8*64 exact).
__device__ inline int chunk_of_block(int bid) {
    return (bid & (NXCD - 1)) * (NSB / NXCD) + (bid >> 3);
}
// Bijective consecutive-buckets -> same-XCD mapping for k6 (3125 = 8*390+5).
__device__ inline int bucket_of_block(int bid) {
    int xcd = bid & 7, idx = bid >> 3;
    int q = NB >> 3, r = NB & 7;                       // 390, 5
    return (xcd < r) ? xcd * (q + 1) + idx
                     : r * (q + 1) + (xcd - r) * q + idx;
}

// ---------- K2: per-chunk bucket histogram + fused exclusive scan ----------
// Writes pscan row: row[b] = exclusive start of bucket b within the chunk,
// row[NB] = chunk (sentinel).
__global__ __launch_bounds__(BLK5) void k2_hist(const int* __restrict__ dst,
                                                unsigned short* __restrict__ bh,
                                                int chunk) {
    __shared__ int h[NB];
    __shared__ int s[BLK5];
    int t = threadIdx.x;
    for (int b = t; b < NB; b += BLK5) h[b] = 0;
    __syncthreads();
    int cblk = chunk_of_block(blockIdx.x);
    long long e0 = (long long)cblk * chunk;
    const vint4* d4 = (const vint4*)(dst + e0);
    int n4 = chunk >> 2;
    int i = t;
    for (; i + 3 * BLK5 < n4; i += 4 * BLK5) {
        vint4 d0 = __builtin_nontemporal_load(&d4[i]);
        vint4 d1 = __builtin_nontemporal_load(&d4[i + BLK5]);
        vint4 d2 = __builtin_nontemporal_load(&d4[i + 2 * BLK5]);
        vint4 d3 = __builtin_nontemporal_load(&d4[i + 3 * BLK5]);
        __builtin_amdgcn_sched_barrier(0);
        atomicAdd(&h[d0[0] >> NPS_SH], 1); atomicAdd(&h[d0[1] >> NPS_SH], 1);
        atomicAdd(&h[d0[2] >> NPS_SH], 1); atomicAdd(&h[d0[3] >> NPS_SH], 1);
        atomicAdd(&h[d1[0] >> NPS_SH], 1); atomicAdd(&h[d1[1] >> NPS_SH], 1);
        atomicAdd(&h[d1[2] >> NPS_SH], 1); atomicAdd(&h[d1[3] >> NPS_SH], 1);
        atomicAdd(&h[d2[0] >> NPS_SH], 1); atomicAdd(&h[d2[1] >> NPS_SH], 1);
        atomicAdd(&h[d2[2] >> NPS_SH], 1); atomicAdd(&h[d2[3] >> NPS_SH], 1);
        atomicAdd(&h[d3[0] >> NPS_SH], 1); atomicAdd(&h[d3[1] >> NPS_SH], 1);
        atomicAdd(&h[d3[2] >> NPS_SH], 1); atomicAdd(&h[d3[3] >> NPS_SH], 1);
    }
    for (; i < n4; i += BLK5) {
        vint4 d = __builtin_nontemporal_load(&d4[i]);
        atomicAdd(&h[d[0] >> NPS_SH], 1); atomicAdd(&h[d[1] >> NPS_SH], 1);
        atomicAdd(&h[d[2] >> NPS_SH], 1); atomicAdd(&h[d[3] >> NPS_SH], 1);
    }
    __syncthreads();
    // Fused exclusive scan over the NB counts (values fit ushort: <= chunk).
    int v[K2VPT], sum = 0;
#pragma unroll
    for (int k = 0; k < K2VPT; ++k) {
        int j = K2VPT * t + k;
        v[k] = (j < NB) ? h[j] : 0;
        sum += v[k];
    }
    s[t] = sum;
    __syncthreads();
    for (int off = 1; off < BLK5; off <<= 1) {
        int u = (t >= off) ? s[t - off] : 0;
        __syncthreads();
        s[t] += u;
        __syncthreads();
    }
    int run = s[t] - sum;
    unsigned short* row = bh + (size_t)cblk * NBP1;
#pragma unroll
    for (int k = 0; k < K2VPT; ++k) {
        int j = K2VPT * t + k;
        if (j < NB) row[j] = (unsigned short)run;
        run += v[k];
    }
    if (t == 0) row[NB] = (unsigned short)chunk;
}

// ---------- K5: chunk-LOCAL scatter of packed (u<<5 | local_dst) -----------
// All stores land in this block's private [cblk*chunk, +chunk) region
// (50KB window -> L2 merges partial lines; HBM write is sequential).
__global__ __launch_bounds__(BLK5) void k5_scatter(const int* __restrict__ src,
                                                   const int* __restrict__ dst,
                                                   const unsigned short* __restrict__ bh,
                                                   int* __restrict__ bdata, int chunk) {
    __shared__ int cur[NB];
    int cblk = chunk_of_block(blockIdx.x);
    const unsigned short* row = bh + (size_t)cblk * NBP1;
    int cbase = cblk * chunk;
    for (int b = threadIdx.x; b < NB; b += BLK5)
        cur[b] = cbase + (int)row[b];
    __syncthreads();
    long long e0 = (long long)cblk * chunk;
    const vint4* d4 = (const vint4*)(dst + e0);
    const vint4* s4 = (const vint4*)(src + e0);
    int n4 = chunk >> 2;
    int i = threadIdx.x;
    for (; i + 3 * BLK5 < n4; i += 4 * BLK5) {
        vint4 d[4], s[4];
#pragma unroll
        for (int k = 0; k < 4; ++k) {
            d[k] = __builtin_nontemporal_load(&d4[i + k * BLK5]);
            s[k] = __builtin_nontemporal_load(&s4[i + k * BLK5]);
        }
        __builtin_amdgcn_sched_barrier(0);
#pragma unroll
        for (int k = 0; k < 4; ++k) {
#pragma unroll
            for (int j = 0; j < 4; ++j) {
                int vv = d[k][j];
                int uu = s[k][j];
                int b = vv >> NPS_SH;
                int off = atomicAdd(&cur[b], 1);
                bdata[off] = (uu << NPS_SH) | (vv & (NPS - 1));  // PLAIN store
            }
        }
    }
    for (; i < n4; i += BLK5) {
        vint4 d = __builtin_nontemporal_load(&d4[i]);
        vint4 s = __builtin_nontemporal_load(&s4[i]);
#pragma unroll
        for (int j = 0; j < 4; ++j) {
            int vv = d[j];
            int uu = s[j];
            int b = vv >> NPS_SH;
            int off = atomicAdd(&cur[b], 1);
            bdata[off] = (uu << NPS_SH) | (vv & (NPS - 1));      // PLAIN store
        }
    }
}

// ---------- K1: bf16-pack rows 5 f32 -> 16 B (after k5: overlaps) ----------
__global__ __launch_bounds__(BLK) void k1_pad(const float* __restrict__ f,
                                              uint4* __restrict__ fp) {
    int i = blockIdx.x * BLK + threadIdx.x;
    if (i < NN) {
        const float* r = f + (long long)i * FD;
        unsigned w0 = bf16rtn(r[0]), w1 = bf16rtn(r[1]), w2 = bf16rtn(r[2]);
        unsigned w3 = bf16rtn(r[3]), w4 = bf16rtn(r[4]);
        uint4 o;
        o.x = w0 | (w1 << 16);
        o.y = w2 | (w3 << 16);
        o.z = w4;
        o.w = 0u;
        fp[i] = o;
    }
}

// ---------- K6: one block per bucket — gather 512 per-chunk sub-ranges into
//              LDS raw, in-LDS counting sort by local node (ONE atomic/edge),
//              register accumulation (8 threads per node), shfl reduce. ------
#define CAP 3072              // window capacity (bucket mean 2048, max ~2.3K)
#define WPT (CAP / BLK)       // 12
__global__ __launch_bounds__(BLK) void k6_gather(const int* __restrict__ bdata,
                                                 const uint4* __restrict__ fp,
                                                 const unsigned short* __restrict__ bh,
                                                 float* __restrict__ out, int chunk) {
    __shared__ int raw[CAP];      // bucket entries in chunk order (12 KB)
    __shared__ int seg[CAP];      // entries sorted by local node (12 KB)
    __shared__ int hist[NPS];
    __shared__ int sbase[NPS];
    __shared__ int s[BLK];
    int t = threadIdx.x;
    int b = bucket_of_block(blockIdx.x);

    // Phase 0: my 2 chunks' sub-range (start,len) + block scan -> positions.
    int c0 = t, c1 = t + BLK;                 // NSB == 2*BLK
    const unsigned short* r0 = bh + (size_t)c0 * NBP1 + b;
    const unsigned short* r1 = bh + (size_t)c1 * NBP1 + b;
    int o0 = r0[0], l0 = (int)r0[1] - o0;
    int o1 = r1[0], l1 = (int)r1[1] - o1;
    int pair = l0 + l1;
    s[t] = pair;
    __syncthreads();
    for (int off = 1; off < BLK; off <<= 1) {
        int u = (t >= off) ? s[t - off] : 0;
        __syncthreads();
        s[t] += u;
        __syncthreads();
    }
    int cum0 = s[t] - pair;       // global rank of my chunk-0 entries
    int cumm = cum0 + l0;         // global rank of my chunk-1 entries
    int n = s[BLK - 1];           // bucket total
    int g0 = c0 * chunk + o0;     // bdata index of my chunk-0 sub-range
    int g1 = c1 * chunk + o1;

    int grp = t >> 3;             // node 0..31 this 8-thread team owns
    int sub = t & 7;
    float a0 = 0.f, a1 = 0.f, a2 = 0.f, a3 = 0.f, a4 = 0.f;

    for (int ws = 0; ws < n; ws += CAP) {
        int we = ws + CAP; if (we > n) we = n;
        int m = we - ws;
        if (t < NPS) hist[t] = 0;
        __syncthreads();

        // Copy intersection of my sub-ranges with window [ws,we) into raw.
        {
            int lo = cum0 > ws ? cum0 : ws;
            int hi = (cum0 + l0) < we ? (cum0 + l0) : we;
            for (int p = lo; p < hi; ++p) raw[p - ws] = bdata[g0 + (p - cum0)];
            lo = cumm > ws ? cumm : ws;
            hi = (cumm + l1) < we ? (cumm + l1) : we;
            for (int p = lo; p < hi; ++p) raw[p - ws] = bdata[g1 + (p - cumm)];
        }
        __syncthreads();

        // Rank pass (the ONLY atomic): w >= 0 always for real entries.
        int w[WPT], rk[WPT];
#pragma unroll
        for (int k = 0; k < WPT; ++k) {
            int idx = t + k * BLK;
            w[k] = (idx < m) ? raw[idx] : -1;
        }
#pragma unroll
        for (int k = 0; k < WPT; ++k)
            rk[k] = (w[k] >= 0) ? atomicAdd(&hist[w[k] & (NPS - 1)], 1) : 0;
        __syncthreads();

        // Exclusive scan of 32 counts (wave 0, lanes 0..31).
        if (t < NPS) {
            int v = hist[t];
            int sc = v;
#pragma unroll
            for (int off = 1; off < NPS; off <<= 1) {
                int u = __shfl_up(sc, off, 64);
                if (t >= off) sc += u;
            }
            sbase[t] = sc - v;
        }
        __syncthreads();

        // Scatter u into node-sorted position (rank known, no atomics).
#pragma unroll
        for (int k = 0; k < WPT; ++k) {
            if (w[k] >= 0)
                seg[sbase[w[k] & (NPS - 1)] + rk[k]] = w[k] >> NPS_SH;
        }
        __syncthreads();

        // Accumulate: 8 threads per node, strided slice, registers only.
        int s0 = sbase[grp], cnt = hist[grp];
        int j = sub;
        for (; j + 24 < cnt; j += 32) {
            int u0 = seg[s0 + j],      u1 = seg[s0 + j + 8];
            int u2 = seg[s0 + j + 16], u3 = seg[s0 + j + 24];
            uint4 q0 = fp[u0], q1 = fp[u1], q2 = fp[u2], q3 = fp[u3];
            a0 += lo16(q0.x); a1 += hi16(q0.x); a2 += lo16(q0.y); a3 += hi16(q0.y); a4 += lo16(q0.z);
            a0 += lo16(q1.x); a1 += hi16(q1.x); a2 += lo16(q1.y); a3 += hi16(q1.y); a4 += lo16(q1.z);
            a0 += lo16(q2.x); a1 += hi16(q2.x); a2 += lo16(q2.y); a3 += hi16(q2.y); a4 += lo16(q2.z);
            a0 += lo16(q3.x); a1 += hi16(q3.x); a2 += lo16(q3.y); a3 += hi16(q3.y); a4 += lo16(q3.z);
        }
        for (; j < cnt; j += 8) {
            int u = seg[s0 + j];
            uint4 q = fp[u];
            a0 += lo16(q.x); a1 += hi16(q.x); a2 += lo16(q.y); a3 += hi16(q.y); a4 += lo16(q.z);
        }
        __syncthreads();   // LDS reused next window
    }

    // Reduce the 8 partials per node within the 8-lane cluster.
    a0 += __shfl_down(a0, 4, 8); a0 += __shfl_down(a0, 2, 8); a0 += __shfl_down(a0, 1, 8);
    a1 += __shfl_down(a1, 4, 8); a1 += __shfl_down(a1, 2, 8); a1 += __shfl_down(a1, 1, 8);
    a2 += __shfl_down(a2, 4, 8); a2 += __shfl_down(a2, 2, 8); a2 += __shfl_down(a2, 1, 8);
    a3 += __shfl_down(a3, 4, 8); a3 += __shfl_down(a3, 2, 8); a3 += __shfl_down(a3, 1, 8);
    a4 += __shfl_down(a4, 4, 8); a4 += __shfl_down(a4, 2, 8); a4 += __shfl_down(a4, 1, 8);
    if (sub == 0) {
        // Exclusive owner; NB*NPS*FD == NOUTT exactly.
        float* o = out + (size_t)b * (NPS * FD) + grp * FD;
        o[0] = a0; o[1] = a1; o[2] = a2; o[3] = a3; o[4] = a4;
    }
}

// ---------- Fallback: direct global atomics ---------------------------------
__global__ void scatter_add_fallback(const float* __restrict__ features,
                                     const int* __restrict__ src,
                                     const int* __restrict__ dst,
                                     float* __restrict__ out, int n_edges) {
    int idx = blockIdx.x * blockDim.x + threadIdx.x;
    int stride = gridDim.x * blockDim.x;
    for (int e = idx; e < n_edges; e += stride) {
        int u = src[e], v = dst[e];
        const float* f = features + (long long)u * FD;
        float* o = out + (long long)v * FD;
#pragma unroll
        for (int k = 0; k < FD; ++k) atomicAdd(&o[k], f[k]);
    }
}

extern "C" void kernel_launch(void* const* d_in, const int* in_sizes, int n_in,
                              void* d_out, int out_size, void* d_ws, size_t ws_size,
                              hipStream_t stream) {
    const float* features = (const float*)d_in[0];
    const int*   src      = (const int*)d_in[1];
    const int*   dst      = (const int*)d_in[2];
    float* out = (float*)d_out;
    int n_edges = in_sizes[1];
    int chunk = n_edges / NSB;

    // ws carve: bdata | bh (pscan rows, LIVE through k6) | fpad.
    size_t o_bd = 0;                                        // bdata: E*4
    size_t o_bh = o_bd + (size_t)n_edges * 4;               // bh: NSB*NBP1*2
    size_t sz_bh = (size_t)NSB * NBP1 * 2;
    size_t o_fp = o_bh + ((sz_bh + 15) & ~(size_t)15);      // fpad: NN*16
    size_t need = o_fp + (size_t)NN * sizeof(uint4);

    bool fast = (out_size == NOUTT) && (in_sizes[0] == NOUTT) &&
                (n_edges % (NSB * 4) == 0) && (chunk <= 65535) &&
                (need <= ws_size);

    if (fast) {
        char* w = (char*)d_ws;
        int*            bdata = (int*)(w + o_bd);
        unsigned short* bh    = (unsigned short*)(w + o_bh);
        uint4*          fpad  = (uint4*)(w + o_fp);
        k2_hist  <<<NSB, BLK5, 0, stream>>>(dst, bh, chunk);
        k5_scatter<<<NSB, BLK5, 0, stream>>>(src, dst, bh, bdata, chunk);
        k1_pad   <<<(NN + BLK - 1) / BLK, BLK, 0, stream>>>(features, fpad);
        k6_gather <<<NB, BLK, 0, stream>>>(bdata, fpad, bh, out, chunk);
    } else {
        (void)hipMemsetAsync(d_out, 0, (size_t)out_size * sizeof(float), stream);
        int grid = (n_edges + BLK - 1) / BLK;
        if (grid > 65535) grid = 65535;
        scatter_add_fallback<<<grid, BLK, 0, stream>>>(features, src, dst, out, n_edges);
    }
}

// Round 4
// 186.964 us; speedup vs baseline: 2.0306x; 1.0173x over previous
//
#include <hip/hip_runtime.h>
#include <hip/hip_bf16.h>

// h_out[v] = sum over edges (u->v) of features[u]
// CHUNK-LOCAL counting sort (k2 hist+scan, k5 private-window scatter), then
// k6: one block per bucket. Round-4 k6 redesign:
//  - bh TRANSPOSED by k7 -> k6 reads its 512 (start,len) pairs as two
//    contiguous 1KB rows (2 coalesced loads/thread) instead of 512 scattered
//    remote-L2 lines per block.
//  - balanced register gather: block-scan of lens (shfl, 2 barriers), then
//    each thread binary-searches its strided positions in LDS cum[] and loads
//    bdata DIRECTLY into registers -- no serial per-thread copy loop, no raw[]
//    buffer. LDS 26KB -> 17KB => 8 blocks/CU for latency hiding.
//  - then the proven in-LDS rank-sort (ONE atomic/edge) + register
//    accumulation (8 threads/node) + shfl reduce + exclusive store.

#define NN     100000
#define FD     5
#define NOUTT  (NN * FD)      // 500000
#define NPS    32             // nodes per bucket
#define NPS_SH 5
#define NB     3125           // 100000 / 32 exactly
#define NBP1   3126           // pscan row length (sentinel row[NB] = chunk)
#define NSB    512            // scatter/hist blocks (chunk = 12500 edges)
#define BLK    256
#define BLK5   512            // wide blocks for k2/k5
#define NXCD   8
#define K2VPT  7              // 7*512 = 3584 >= 3125 (k2 tail scan)

typedef int vint4 __attribute__((ext_vector_type(4)));

__device__ inline unsigned bf16rtn(float x) {          // fp32 -> bf16 (RTN)
    unsigned u = __float_as_uint(x);
    u += 0x7fffu + ((u >> 16) & 1u);
    return u >> 16;
}
__device__ inline float lo16(unsigned v) { return __uint_as_float(v << 16); }
__device__ inline float hi16(unsigned v) { return __uint_as_float(v & 0xffff0000u); }

// XCD-contiguous chunk assignment for k2/k5 (512 = 8*64 exact).
__device__ inline int chunk_of_block(int bid) {
    return (bid & (NXCD - 1)) * (NSB / NXCD) + (bid >> 3);
}
// Bijective consecutive-buckets -> same-XCD mapping for k6 (3125 = 8*390+5).
__device__ inline int bucket_of_block(int bid) {
    int xcd = bid & 7, idx = bid >> 3;
    int q = NB >> 3, r = NB & 7;                       // 390, 5
    return (xcd < r) ? xcd * (q + 1) + idx
                     : r * (q + 1) + (xcd - r) * q + idx;
}

// ---------- K2: per-chunk bucket histogram + fused exclusive scan ----------
__global__ __launch_bounds__(BLK5) void k2_hist(const int* __restrict__ dst,
                                                unsigned short* __restrict__ bh,
                                                int chunk) {
    __shared__ int h[NB];
    __shared__ int s[BLK5];
    int t = threadIdx.x;
    for (int b = t; b < NB; b += BLK5) h[b] = 0;
    __syncthreads();
    int cblk = chunk_of_block(blockIdx.x);
    long long e0 = (long long)cblk * chunk;
    const vint4* d4 = (const vint4*)(dst + e0);
    int n4 = chunk >> 2;
    int i = t;
    for (; i + 3 * BLK5 < n4; i += 4 * BLK5) {
        vint4 d0 = __builtin_nontemporal_load(&d4[i]);
        vint4 d1 = __builtin_nontemporal_load(&d4[i + BLK5]);
        vint4 d2 = __builtin_nontemporal_load(&d4[i + 2 * BLK5]);
        vint4 d3 = __builtin_nontemporal_load(&d4[i + 3 * BLK5]);
        __builtin_amdgcn_sched_barrier(0);
        atomicAdd(&h[d0[0] >> NPS_SH], 1); atomicAdd(&h[d0[1] >> NPS_SH], 1);
        atomicAdd(&h[d0[2] >> NPS_SH], 1); atomicAdd(&h[d0[3] >> NPS_SH], 1);
        atomicAdd(&h[d1[0] >> NPS_SH], 1); atomicAdd(&h[d1[1] >> NPS_SH], 1);
        atomicAdd(&h[d1[2] >> NPS_SH], 1); atomicAdd(&h[d1[3] >> NPS_SH], 1);
        atomicAdd(&h[d2[0] >> NPS_SH], 1); atomicAdd(&h[d2[1] >> NPS_SH], 1);
        atomicAdd(&h[d2[2] >> NPS_SH], 1); atomicAdd(&h[d2[3] >> NPS_SH], 1);
        atomicAdd(&h[d3[0] >> NPS_SH], 1); atomicAdd(&h[d3[1] >> NPS_SH], 1);
        atomicAdd(&h[d3[2] >> NPS_SH], 1); atomicAdd(&h[d3[3] >> NPS_SH], 1);
    }
    for (; i < n4; i += BLK5) {
        vint4 d = __builtin_nontemporal_load(&d4[i]);
        atomicAdd(&h[d[0] >> NPS_SH], 1); atomicAdd(&h[d[1] >> NPS_SH], 1);
        atomicAdd(&h[d[2] >> NPS_SH], 1); atomicAdd(&h[d[3] >> NPS_SH], 1);
    }
    __syncthreads();
    // Fused exclusive scan over the NB counts (values fit ushort: <= chunk).
    int v[K2VPT], sum = 0;
#pragma unroll
    for (int k = 0; k < K2VPT; ++k) {
        int j = K2VPT * t + k;
        v[k] = (j < NB) ? h[j] : 0;
        sum += v[k];
    }
    s[t] = sum;
    __syncthreads();
    for (int off = 1; off < BLK5; off <<= 1) {
        int u = (t >= off) ? s[t - off] : 0;
        __syncthreads();
        s[t] += u;
        __syncthreads();
    }
    int run = s[t] - sum;
    unsigned short* row = bh + (size_t)cblk * NBP1;
#pragma unroll
    for (int k = 0; k < K2VPT; ++k) {
        int j = K2VPT * t + k;
        if (j < NB) row[j] = (unsigned short)run;
        run += v[k];
    }
    if (t == 0) row[NB] = (unsigned short)chunk;
}

// ---------- K7: transpose bh [chunk][bucket] -> bhT [bucket][chunk] --------
// bhT row b is contiguous: k6 reads its 512 starts with 2 coalesced loads.
#define TD 64
__global__ __launch_bounds__(256) void k7_transpose(const unsigned short* __restrict__ bh,
                                                    unsigned short* __restrict__ bhT) {
    __shared__ unsigned short tile[TD][TD + 1];
    int jx = blockIdx.x * TD;      // bucket-dim tile origin
    int cy = blockIdx.y * TD;      // chunk-dim tile origin
    int tx = threadIdx.x & (TD - 1);
    int ty = threadIdx.x >> 6;     // 0..3
#pragma unroll
    for (int r = 0; r < 16; ++r) {
        int c = cy + ty + 4 * r;
        int j = jx + tx;
        tile[ty + 4 * r][tx] =
            (j < NBP1) ? bh[(size_t)c * NBP1 + j] : (unsigned short)0;
    }
    __syncthreads();
#pragma unroll
    for (int r = 0; r < 16; ++r) {
        int j = jx + ty + 4 * r;
        int c = cy + tx;
        if (j < NBP1) bhT[(size_t)j * NSB + c] = tile[tx][ty + 4 * r];
    }
}

// ---------- K5: chunk-LOCAL scatter of packed (u<<5 | local_dst) -----------
__global__ __launch_bounds__(BLK5) void k5_scatter(const int* __restrict__ src,
                                                   const int* __restrict__ dst,
                                                   const unsigned short* __restrict__ bh,
                                                   int* __restrict__ bdata, int chunk) {
    __shared__ int cur[NB];
    int cblk = chunk_of_block(blockIdx.x);
    const unsigned short* row = bh + (size_t)cblk * NBP1;
    int cbase = cblk * chunk;
    for (int b = threadIdx.x; b < NB; b += BLK5)
        cur[b] = cbase + (int)row[b];
    __syncthreads();
    long long e0 = (long long)cblk * chunk;
    const vint4* d4 = (const vint4*)(dst + e0);
    const vint4* s4 = (const vint4*)(src + e0);
    int n4 = chunk >> 2;
    int i = threadIdx.x;
    for (; i + 3 * BLK5 < n4; i += 4 * BLK5) {
        vint4 d[4], s[4];
#pragma unroll
        for (int k = 0; k < 4; ++k) {
            d[k] = __builtin_nontemporal_load(&d4[i + k * BLK5]);
            s[k] = __builtin_nontemporal_load(&s4[i + k * BLK5]);
        }
        __builtin_amdgcn_sched_barrier(0);
#pragma unroll
        for (int k = 0; k < 4; ++k) {
#pragma unroll
            for (int j = 0; j < 4; ++j) {
                int vv = d[k][j];
                int uu = s[k][j];
                int b = vv >> NPS_SH;
                int off = atomicAdd(&cur[b], 1);
                bdata[off] = (uu << NPS_SH) | (vv & (NPS - 1));  // PLAIN store
            }
        }
    }
    for (; i < n4; i += BLK5) {
        vint4 d = __builtin_nontemporal_load(&d4[i]);
        vint4 s = __builtin_nontemporal_load(&s4[i]);
#pragma unroll
        for (int j = 0; j < 4; ++j) {
            int vv = d[j];
            int uu = s[j];
            int b = vv >> NPS_SH;
            int off = atomicAdd(&cur[b], 1);
            bdata[off] = (uu << NPS_SH) | (vv & (NPS - 1));      // PLAIN store
        }
    }
}

// ---------- K1: bf16-pack rows 5 f32 -> 16 B --------------------------------
__global__ __launch_bounds__(BLK) void k1_pad(const float* __restrict__ f,
                                              uint4* __restrict__ fp) {
    int i = blockIdx.x * BLK + threadIdx.x;
    if (i < NN) {
        const float* r = f + (long long)i * FD;
        unsigned w0 = bf16rtn(r[0]), w1 = bf16rtn(r[1]), w2 = bf16rtn(r[2]);
        unsigned w3 = bf16rtn(r[3]), w4 = bf16rtn(r[4]);
        uint4 o;
        o.x = w0 | (w1 << 16);
        o.y = w2 | (w3 << 16);
        o.z = w4;
        o.w = 0u;
        fp[i] = o;
    }
}

// ---------- K6: one block per bucket -----------------------------------------
#define CAP 3072              // window capacity (bucket mean 2048, max ~2.3K)
#define WPT (CAP / BLK)       // 12
__global__ __launch_bounds__(BLK) void k6_gather(const int* __restrict__ bdata,
                                                 const uint4* __restrict__ fp,
                                                 const unsigned short* __restrict__ bhT,
                                                 float* __restrict__ out, int chunk) {
    __shared__ int seg[CAP];          // entries sorted by local node (12 KB)
    __shared__ int cum[NSB + 1];      // global exclusive position per chunk
    __shared__ int gst[NSB];          // bdata index of each chunk's sub-range
    __shared__ int hist[NPS];
    __shared__ int sbase[NPS];
    __shared__ int wsum[BLK / 64];
    int t = threadIdx.x;
    int b = bucket_of_block(blockIdx.x);

    // Phase 0: coalesced (start,len) for chunks 2t,2t+1 from bhT rows b,b+1.
    const unsigned* r0 = (const unsigned*)(bhT + (size_t)b * NSB);
    const unsigned* r1 = (const unsigned*)(bhT + (size_t)(b + 1) * NSB);
    unsigned s0 = r0[t], s1 = r1[t];
    int st0 = (int)(s0 & 0xffffu), st1 = (int)(s0 >> 16);
    int l0 = (int)(s1 & 0xffffu) - st0;
    int l1 = (int)(s1 >> 16) - st1;
    int pair = l0 + l1;
    // wave-inclusive scan of pair (shfl; no barriers)
    int lane = t & 63, wid = t >> 6;
    int sc = pair;
#pragma unroll
    for (int off = 1; off < 64; off <<= 1) {
        int u = __shfl_up(sc, off, 64);
        if (lane >= off) sc += u;
    }
    if (lane == 63) wsum[wid] = sc;
    __syncthreads();
    int w0s = wsum[0], w1s = wsum[1], w2s = wsum[2], w3s = wsum[3];
    int woff = (wid > 0 ? w0s : 0) + (wid > 1 ? w1s : 0) + (wid > 2 ? w2s : 0);
    int n = w0s + w1s + w2s + w3s;            // bucket total
    int exc = woff + sc - pair;               // global rank of chunk 2t start
    cum[2 * t]     = exc;
    cum[2 * t + 1] = exc + l0;
    gst[2 * t]     = 2 * t * chunk + st0;
    gst[2 * t + 1] = (2 * t + 1) * chunk + st1;
    if (t == 0) cum[NSB] = n;
    // (first in-loop barrier publishes cum/gst)

    int grp = t >> 3;             // node 0..31 this 8-thread team owns
    int sub = t & 7;
    float a0 = 0.f, a1 = 0.f, a2 = 0.f, a3 = 0.f, a4 = 0.f;

    for (int ws = 0; ws < n; ws += CAP) {
        int we = ws + CAP; if (we > n) we = n;
        int m = we - ws;
        if (t < NPS) hist[t] = 0;
        __syncthreads();

        // Balanced register gather: position -> (chunk via binary search) ->
        // direct bdata load. 12 independent searches/loads per thread (ILP).
        int w[WPT], rk[WPT];
#pragma unroll
        for (int k = 0; k < WPT; ++k) {
            int idx = t + k * BLK;
            w[k] = -1;
            if (idx < m) {
                int p = ws + idx;
                int lo = 0;
#pragma unroll
                for (int stp = 256; stp > 0; stp >>= 1) {
                    int mid = lo + stp;                 // <= 512 always
                    lo = (cum[mid] <= p) ? mid : lo;
                }
                w[k] = bdata[gst[lo] + (p - cum[lo])];
            }
        }
        // Rank pass (the ONLY atomic): w >= 0 always for real entries.
#pragma unroll
        for (int k = 0; k < WPT; ++k)
            rk[k] = (w[k] >= 0) ? atomicAdd(&hist[w[k] & (NPS - 1)], 1) : 0;
        __syncthreads();

        // Exclusive scan of 32 counts (wave 0, lanes 0..31).
        if (t < NPS) {
            int v = hist[t];
            int scn = v;
#pragma unroll
            for (int off = 1; off < NPS; off <<= 1) {
                int u = __shfl_up(scn, off, 64);
                if (t >= off) scn += u;
            }
            sbase[t] = scn - v;
        }
        __syncthreads();

        // Scatter u into node-sorted position (rank known, no atomics).
#pragma unroll
        for (int k = 0; k < WPT; ++k) {
            if (w[k] >= 0)
                seg[sbase[w[k] & (NPS - 1)] + rk[k]] = w[k] >> NPS_SH;
        }
        __syncthreads();

        // Accumulate: 8 threads per node, strided slice, registers only.
        int sg0 = sbase[grp], cnt = hist[grp];
        int j = sub;
        for (; j + 24 < cnt; j += 32) {
            int u0 = seg[sg0 + j],      u1 = seg[sg0 + j + 8];
            int u2 = seg[sg0 + j + 16], u3 = seg[sg0 + j + 24];
            uint4 q0 = fp[u0], q1 = fp[u1], q2 = fp[u2], q3 = fp[u3];
            a0 += lo16(q0.x); a1 += hi16(q0.x); a2 += lo16(q0.y); a3 += hi16(q0.y); a4 += lo16(q0.z);
            a0 += lo16(q1.x); a1 += hi16(q1.x); a2 += lo16(q1.y); a3 += hi16(q1.y); a4 += lo16(q1.z);
            a0 += lo16(q2.x); a1 += hi16(q2.x); a2 += lo16(q2.y); a3 += hi16(q2.y); a4 += lo16(q2.z);
            a0 += lo16(q3.x); a1 += hi16(q3.x); a2 += lo16(q3.y); a3 += hi16(q3.y); a4 += lo16(q3.z);
        }
        for (; j < cnt; j += 8) {
            int u = seg[sg0 + j];
            uint4 q = fp[u];
            a0 += lo16(q.x); a1 += hi16(q.x); a2 += lo16(q.y); a3 += hi16(q.y); a4 += lo16(q.z);
        }
        __syncthreads();   // LDS reused next window
    }

    // Reduce the 8 partials per node within the 8-lane cluster.
    a0 += __shfl_down(a0, 4, 8); a0 += __shfl_down(a0, 2, 8); a0 += __shfl_down(a0, 1, 8);
    a1 += __shfl_down(a1, 4, 8); a1 += __shfl_down(a1, 2, 8); a1 += __shfl_down(a1, 1, 8);
    a2 += __shfl_down(a2, 4, 8); a2 += __shfl_down(a2, 2, 8); a2 += __shfl_down(a2, 1, 8);
    a3 += __shfl_down(a3, 4, 8); a3 += __shfl_down(a3, 2, 8); a3 += __shfl_down(a3, 1, 8);
    a4 += __shfl_down(a4, 4, 8); a4 += __shfl_down(a4, 2, 8); a4 += __shfl_down(a4, 1, 8);
    if (sub == 0) {
        // Exclusive owner; NB*NPS*FD == NOUTT exactly.
        float* o = out + (size_t)b * (NPS * FD) + grp * FD;
        o[0] = a0; o[1] = a1; o[2] = a2; o[3] = a3; o[4] = a4;
    }
}

// ---------- Fallback: direct global atomics ---------------------------------
__global__ void scatter_add_fallback(const float* __restrict__ features,
                                     const int* __restrict__ src,
                                     const int* __restrict__ dst,
                                     float* __restrict__ out, int n_edges) {
    int idx = blockIdx.x * blockDim.x + threadIdx.x;
    int stride = gridDim.x * blockDim.x;
    for (int e = idx; e < n_edges; e += stride) {
        int u = src[e], v = dst[e];
        const float* f = features + (long long)u * FD;
        float* o = out + (long long)v * FD;
#pragma unroll
        for (int k = 0; k < FD; ++k) atomicAdd(&o[k], f[k]);
    }
}

extern "C" void kernel_launch(void* const* d_in, const int* in_sizes, int n_in,
                              void* d_out, int out_size, void* d_ws, size_t ws_size,
                              hipStream_t stream) {
    const float* features = (const float*)d_in[0];
    const int*   src      = (const int*)d_in[1];
    const int*   dst      = (const int*)d_in[2];
    float* out = (float*)d_out;
    int n_edges = in_sizes[1];
    int chunk = n_edges / NSB;

    // ws carve: bdata | bh | bhT | fpad (bh & bhT live through k6).
    size_t o_bd = 0;                                        // bdata: E*4
    size_t o_bh = o_bd + (size_t)n_edges * 4;               // bh:  NSB*NBP1*2
    size_t sz_bh = (size_t)NSB * NBP1 * 2;
    size_t o_bt = o_bh + ((sz_bh + 15) & ~(size_t)15);      // bhT: NBP1*NSB*2
    size_t o_fp = o_bt + ((sz_bh + 15) & ~(size_t)15);      // fpad: NN*16
    size_t need = o_fp + (size_t)NN * sizeof(uint4);

    bool fast = (out_size == NOUTT) && (in_sizes[0] == NOUTT) &&
                (n_edges % (NSB * 4) == 0) && (chunk <= 65535) &&
                (need <= ws_size);

    if (fast) {
        char* w = (char*)d_ws;
        int*            bdata = (int*)(w + o_bd);
        unsigned short* bh    = (unsigned short*)(w + o_bh);
        unsigned short* bhT   = (unsigned short*)(w + o_bt);
        uint4*          fpad  = (uint4*)(w + o_fp);
        dim3 g7((NBP1 + TD - 1) / TD, NSB / TD);
        k2_hist    <<<NSB, BLK5, 0, stream>>>(dst, bh, chunk);
        k7_transpose<<<g7, 256, 0, stream>>>(bh, bhT);
        k5_scatter <<<NSB, BLK5, 0, stream>>>(src, dst, bh, bdata, chunk);
        k1_pad     <<<(NN + BLK - 1) / BLK, BLK, 0, stream>>>(features, fpad);
        k6_gather  <<<NB, BLK, 0, stream>>>(bdata, fpad, bhT, out, chunk);
    } else {
        (void)hipMemsetAsync(d_out, 0, (size_t)out_size * sizeof(float), stream);
        int grid = (n_edges + BLK - 1) / BLK;
        if (grid > 65535) grid = 65535;
        scatter_add_fallback<<<grid, BLK, 0, stream>>>(features, src, dst, out, n_edges);
    }
}

// Round 5
// 176.434 us; speedup vs baseline: 2.1518x; 1.0597x over previous
//
#include <hip/hip_runtime.h>
#include <hip/hip_bf16.h>

// h_out[v] = sum over edges (u->v) of features[u]
// Round-5: k2+k5 FUSED into k25 (hist + shfl-scan + scatter in one kernel,
// 1024 threads -> 32 waves/CU = 100% occupancy vs 24%; chunk's dst slice is
// L2-resident between the two passes). k7 transpose, k1 pack, k6 gather
// carried over unchanged from round 4.

#define NN     100000
#define FD     5
#define NOUTT  (NN * FD)      // 500000
#define NPS    32             // nodes per bucket
#define NPS_SH 5
#define NB     3125           // 100000 / 32 exactly
#define NBP1   3126           // pscan row length (sentinel row[NB] = chunk)
#define NSB    512            // chunks (chunk = 12500 edges)
#define BLK    256
#define BLK25  1024           // k25 block (2 blocks/CU = 32 waves/CU)
#define K25VPT 4              // 4*1024 = 4096 >= 3125
#define NXCD   8

typedef int vint4 __attribute__((ext_vector_type(4)));

__device__ inline unsigned bf16rtn(float x) {          // fp32 -> bf16 (RTN)
    unsigned u = __float_as_uint(x);
    u += 0x7fffu + ((u >> 16) & 1u);
    return u >> 16;
}
__device__ inline float lo16(unsigned v) { return __uint_as_float(v << 16); }
__device__ inline float hi16(unsigned v) { return __uint_as_float(v & 0xffff0000u); }

// XCD-contiguous chunk assignment (512 = 8*64 exact).
__device__ inline int chunk_of_block(int bid) {
    return (bid & (NXCD - 1)) * (NSB / NXCD) + (bid >> 3);
}
// Bijective consecutive-buckets -> same-XCD mapping for k6 (3125 = 8*390+5).
__device__ inline int bucket_of_block(int bid) {
    int xcd = bid & 7, idx = bid >> 3;
    int q = NB >> 3, r = NB & 7;                       // 390, 5
    return (xcd < r) ? xcd * (q + 1) + idx
                     : r * (q + 1) + (xcd - r) * q + idx;
}

// ---------- K25: fused per-chunk hist + exclusive scan + local scatter ------
// Pass 1: histogram (plain dst loads -> L2-resident for pass 2).
// Scan: per-thread 4 counts, wave shfl-scan, ONE barrier.
// Pass 2: scatter packed (u<<5|local) into this chunk's private bdata window.
__global__ __launch_bounds__(BLK25, 8) void k25_sortchunk(
        const int* __restrict__ src, const int* __restrict__ dst,
        unsigned short* __restrict__ bh, int* __restrict__ bdata, int chunk) {
    __shared__ int h[NB];         // counts -> then absolute cur[] cursors
    __shared__ int wv[16];
    int t = threadIdx.x;
    for (int b = t; b < NB; b += BLK25) h[b] = 0;
    __syncthreads();
    int cblk = chunk_of_block(blockIdx.x);
    long long e0 = (long long)cblk * chunk;
    const vint4* d4 = (const vint4*)(dst + e0);
    int n4 = chunk >> 2;
    // Pass 1: histogram.
    for (int i = t; i < n4; i += BLK25) {
        vint4 d = d4[i];
        atomicAdd(&h[d[0] >> NPS_SH], 1); atomicAdd(&h[d[1] >> NPS_SH], 1);
        atomicAdd(&h[d[2] >> NPS_SH], 1); atomicAdd(&h[d[3] >> NPS_SH], 1);
    }
    __syncthreads();
    // Shfl-based exclusive scan of the NB counts (values fit ushort).
    int v[K25VPT], sum = 0;
#pragma unroll
    for (int k = 0; k < K25VPT; ++k) {
        int j = K25VPT * t + k;
        v[k] = (j < NB) ? h[j] : 0;
        sum += v[k];
    }
    int lane = t & 63, wid = t >> 6;
    int sc = sum;
#pragma unroll
    for (int off = 1; off < 64; off <<= 1) {
        int u = __shfl_up(sc, off, 64);
        if (lane >= off) sc += u;
    }
    if (lane == 63) wv[wid] = sc;
    __syncthreads();
    int woff = 0;
#pragma unroll
    for (int w2 = 0; w2 < 16; ++w2) woff += (w2 < wid) ? wv[w2] : 0;
    int run = woff + sc - sum;    // exclusive prefix for j = 4t
    int cbase = cblk * chunk;
    unsigned short* row = bh + (size_t)cblk * NBP1;
#pragma unroll
    for (int k = 0; k < K25VPT; ++k) {
        int j = K25VPT * t + k;
        if (j < NB) { row[j] = (unsigned short)run; h[j] = cbase + run; }
        run += v[k];
    }
    if (t == 0) row[NB] = (unsigned short)chunk;
    __syncthreads();
    // Pass 2: scatter (dst re-read = L2 hit; src read-once nontemporal).
    const vint4* s4 = (const vint4*)(src + e0);
    for (int i = t; i < n4; i += BLK25) {
        vint4 d = d4[i];
        vint4 sv = __builtin_nontemporal_load(&s4[i]);
#pragma unroll
        for (int j = 0; j < 4; ++j) {
            int vv = d[j], uu = sv[j];
            int b = vv >> NPS_SH;
            int off = atomicAdd(&h[b], 1);
            bdata[off] = (uu << NPS_SH) | (vv & (NPS - 1));  // PLAIN store
        }
    }
}

// ---------- K7: transpose bh [chunk][bucket] -> bhT [bucket][chunk] --------
#define TD 64
__global__ __launch_bounds__(256) void k7_transpose(const unsigned short* __restrict__ bh,
                                                    unsigned short* __restrict__ bhT) {
    __shared__ unsigned short tile[TD][TD + 1];
    int jx = blockIdx.x * TD;      // bucket-dim tile origin
    int cy = blockIdx.y * TD;      // chunk-dim tile origin
    int tx = threadIdx.x & (TD - 1);
    int ty = threadIdx.x >> 6;     // 0..3
#pragma unroll
    for (int r = 0; r < 16; ++r) {
        int c = cy + ty + 4 * r;
        int j = jx + tx;
        tile[ty + 4 * r][tx] =
            (j < NBP1) ? bh[(size_t)c * NBP1 + j] : (unsigned short)0;
    }
    __syncthreads();
#pragma unroll
    for (int r = 0; r < 16; ++r) {
        int j = jx + ty + 4 * r;
        int c = cy + tx;
        if (j < NBP1) bhT[(size_t)j * NSB + c] = tile[tx][ty + 4 * r];
    }
}

// ---------- K1: bf16-pack rows 5 f32 -> 16 B --------------------------------
__global__ __launch_bounds__(BLK) void k1_pad(const float* __restrict__ f,
                                              uint4* __restrict__ fp) {
    int i = blockIdx.x * BLK + threadIdx.x;
    if (i < NN) {
        const float* r = f + (long long)i * FD;
        unsigned w0 = bf16rtn(r[0]), w1 = bf16rtn(r[1]), w2 = bf16rtn(r[2]);
        unsigned w3 = bf16rtn(r[3]), w4 = bf16rtn(r[4]);
        uint4 o;
        o.x = w0 | (w1 << 16);
        o.y = w2 | (w3 << 16);
        o.z = w4;
        o.w = 0u;
        fp[i] = o;
    }
}

// ---------- K6: one block per bucket (unchanged from round 4) ---------------
#define CAP 3072              // window capacity (bucket mean 2048, max ~2.3K)
#define WPT (CAP / BLK)       // 12
__global__ __launch_bounds__(BLK) void k6_gather(const int* __restrict__ bdata,
                                                 const uint4* __restrict__ fp,
                                                 const unsigned short* __restrict__ bhT,
                                                 float* __restrict__ out, int chunk) {
    __shared__ int seg[CAP];          // entries sorted by local node (12 KB)
    __shared__ int cum[NSB + 1];      // global exclusive position per chunk
    __shared__ int gst[NSB];          // bdata index of each chunk's sub-range
    __shared__ int hist[NPS];
    __shared__ int sbase[NPS];
    __shared__ int wsum[BLK / 64];
    int t = threadIdx.x;
    int b = bucket_of_block(blockIdx.x);

    // Phase 0: coalesced (start,len) for chunks 2t,2t+1 from bhT rows b,b+1.
    const unsigned* r0 = (const unsigned*)(bhT + (size_t)b * NSB);
    const unsigned* r1 = (const unsigned*)(bhT + (size_t)(b + 1) * NSB);
    unsigned s0 = r0[t], s1 = r1[t];
    int st0 = (int)(s0 & 0xffffu), st1 = (int)(s0 >> 16);
    int l0 = (int)(s1 & 0xffffu) - st0;
    int l1 = (int)(s1 >> 16) - st1;
    int pair = l0 + l1;
    // wave-inclusive scan of pair (shfl; no barriers)
    int lane = t & 63, wid = t >> 6;
    int sc = pair;
#pragma unroll
    for (int off = 1; off < 64; off <<= 1) {
        int u = __shfl_up(sc, off, 64);
        if (lane >= off) sc += u;
    }
    if (lane == 63) wsum[wid] = sc;
    __syncthreads();
    int w0s = wsum[0], w1s = wsum[1], w2s = wsum[2], w3s = wsum[3];
    int woff = (wid > 0 ? w0s : 0) + (wid > 1 ? w1s : 0) + (wid > 2 ? w2s : 0);
    int n = w0s + w1s + w2s + w3s;            // bucket total
    int exc = woff + sc - pair;               // global rank of chunk 2t start
    cum[2 * t]     = exc;
    cum[2 * t + 1] = exc + l0;
    gst[2 * t]     = 2 * t * chunk + st0;
    gst[2 * t + 1] = (2 * t + 1) * chunk + st1;
    if (t == 0) cum[NSB] = n;
    // (first in-loop barrier publishes cum/gst)

    int grp = t >> 3;             // node 0..31 this 8-thread team owns
    int sub = t & 7;
    float a0 = 0.f, a1 = 0.f, a2 = 0.f, a3 = 0.f, a4 = 0.f;

    for (int ws = 0; ws < n; ws += CAP) {
        int we = ws + CAP; if (we > n) we = n;
        int m = we - ws;
        if (t < NPS) hist[t] = 0;
        __syncthreads();

        // Balanced register gather: position -> (chunk via binary search) ->
        // direct bdata load. 12 independent searches/loads per thread (ILP).
        int w[WPT], rk[WPT];
#pragma unroll
        for (int k = 0; k < WPT; ++k) {
            int idx = t + k * BLK;
            w[k] = -1;
            if (idx < m) {
                int p = ws + idx;
                int lo = 0;
#pragma unroll
                for (int stp = 256; stp > 0; stp >>= 1) {
                    int mid = lo + stp;                 // <= 512 always
                    lo = (cum[mid] <= p) ? mid : lo;
                }
                w[k] = bdata[gst[lo] + (p - cum[lo])];
            }
        }
        // Rank pass (the ONLY atomic): w >= 0 always for real entries.
#pragma unroll
        for (int k = 0; k < WPT; ++k)
            rk[k] = (w[k] >= 0) ? atomicAdd(&hist[w[k] & (NPS - 1)], 1) : 0;
        __syncthreads();

        // Exclusive scan of 32 counts (wave 0, lanes 0..31).
        if (t < NPS) {
            int v = hist[t];
            int scn = v;
#pragma unroll
            for (int off = 1; off < NPS; off <<= 1) {
                int u = __shfl_up(scn, off, 64);
                if (t >= off) scn += u;
            }
            sbase[t] = scn - v;
        }
        __syncthreads();

        // Scatter u into node-sorted position (rank known, no atomics).
#pragma unroll
        for (int k = 0; k < WPT; ++k) {
            if (w[k] >= 0)
                seg[sbase[w[k] & (NPS - 1)] + rk[k]] = w[k] >> NPS_SH;
        }
        __syncthreads();

        // Accumulate: 8 threads per node, strided slice, registers only.
        int sg0 = sbase[grp], cnt = hist[grp];
        int j = sub;
        for (; j + 24 < cnt; j += 32) {
            int u0 = seg[sg0 + j],      u1 = seg[sg0 + j + 8];
            int u2 = seg[sg0 + j + 16], u3 = seg[sg0 + j + 24];
            uint4 q0 = fp[u0], q1 = fp[u1], q2 = fp[u2], q3 = fp[u3];
            a0 += lo16(q0.x); a1 += hi16(q0.x); a2 += lo16(q0.y); a3 += hi16(q0.y); a4 += lo16(q0.z);
            a0 += lo16(q1.x); a1 += hi16(q1.x); a2 += lo16(q1.y); a3 += hi16(q1.y); a4 += lo16(q1.z);
            a0 += lo16(q2.x); a1 += hi16(q2.x); a2 += lo16(q2.y); a3 += hi16(q2.y); a4 += lo16(q2.z);
            a0 += lo16(q3.x); a1 += hi16(q3.x); a2 += lo16(q3.y); a3 += hi16(q3.y); a4 += lo16(q3.z);
        }
        for (; j < cnt; j += 8) {
            int u = seg[sg0 + j];
            uint4 q = fp[u];
            a0 += lo16(q.x); a1 += hi16(q.x); a2 += lo16(q.y); a3 += hi16(q.y); a4 += lo16(q.z);
        }
        __syncthreads();   // LDS reused next window
    }

    // Reduce the 8 partials per node within the 8-lane cluster.
    a0 += __shfl_down(a0, 4, 8); a0 += __shfl_down(a0, 2, 8); a0 += __shfl_down(a0, 1, 8);
    a1 += __shfl_down(a1, 4, 8); a1 += __shfl_down(a1, 2, 8); a1 += __shfl_down(a1, 1, 8);
    a2 += __shfl_down(a2, 4, 8); a2 += __shfl_down(a2, 2, 8); a2 += __shfl_down(a2, 1, 8);
    a3 += __shfl_down(a3, 4, 8); a3 += __shfl_down(a3, 2, 8); a3 += __shfl_down(a3, 1, 8);
    a4 += __shfl_down(a4, 4, 8); a4 += __shfl_down(a4, 2, 8); a4 += __shfl_down(a4, 1, 8);
    if (sub == 0) {
        // Exclusive owner; NB*NPS*FD == NOUTT exactly.
        float* o = out + (size_t)b * (NPS * FD) + grp * FD;
        o[0] = a0; o[1] = a1; o[2] = a2; o[3] = a3; o[4] = a4;
    }
}

// ---------- Fallback: direct global atomics ---------------------------------
__global__ void scatter_add_fallback(const float* __restrict__ features,
                                     const int* __restrict__ src,
                                     const int* __restrict__ dst,
                                     float* __restrict__ out, int n_edges) {
    int idx = blockIdx.x * blockDim.x + threadIdx.x;
    int stride = gridDim.x * blockDim.x;
    for (int e = idx; e < n_edges; e += stride) {
        int u = src[e], v = dst[e];
        const float* f = features + (long long)u * FD;
        float* o = out + (long long)v * FD;
#pragma unroll
        for (int k = 0; k < FD; ++k) atomicAdd(&o[k], f[k]);
    }
}

extern "C" void kernel_launch(void* const* d_in, const int* in_sizes, int n_in,
                              void* d_out, int out_size, void* d_ws, size_t ws_size,
                              hipStream_t stream) {
    const float* features = (const float*)d_in[0];
    const int*   src      = (const int*)d_in[1];
    const int*   dst      = (const int*)d_in[2];
    float* out = (float*)d_out;
    int n_edges = in_sizes[1];
    int chunk = n_edges / NSB;

    // ws carve: bdata | bh | bhT. fpad OVERLAPS bh (bh dead after k7; k1
    // runs after k7).
    size_t o_bd = 0;                                        // bdata: E*4
    size_t o_bh = o_bd + (size_t)n_edges * 4;               // bh:  NSB*NBP1*2
    size_t sz_bh = (size_t)NSB * NBP1 * 2;                  // 3.2MB
    size_t o_bt = o_bh + ((sz_bh + 15) & ~(size_t)15);      // bhT: NBP1*NSB*2
    size_t o_fp = o_bh;                                     // fpad: NN*16 (1.6MB <= sz_bh)
    size_t need = o_bt + ((sz_bh + 15) & ~(size_t)15);

    bool fast = (out_size == NOUTT) && (in_sizes[0] == NOUTT) &&
                (n_edges % (NSB * 4) == 0) && (chunk <= 65535) &&
                (need <= ws_size);

    if (fast) {
        char* w = (char*)d_ws;
        int*            bdata = (int*)(w + o_bd);
        unsigned short* bh    = (unsigned short*)(w + o_bh);
        unsigned short* bhT   = (unsigned short*)(w + o_bt);
        uint4*          fpad  = (uint4*)(w + o_fp);
        dim3 g7((NBP1 + TD - 1) / TD, NSB / TD);
        k25_sortchunk<<<NSB, BLK25, 0, stream>>>(src, dst, bh, bdata, chunk);
        k7_transpose <<<g7, 256, 0, stream>>>(bh, bhT);
        k1_pad       <<<(NN + BLK - 1) / BLK, BLK, 0, stream>>>(features, fpad);
        k6_gather    <<<NB, BLK, 0, stream>>>(bdata, fpad, bhT, out, chunk);
    } else {
        (void)hipMemsetAsync(d_out, 0, (size_t)out_size * sizeof(float), stream);
        int grid = (n_edges + BLK - 1) / BLK;
        if (grid > 65535) grid = 65535;
        scatter_add_fallback<<<grid, BLK, 0, stream>>>(features, src, dst, out, n_edges);
    }
}

// Round 6
// 151.924 us; speedup vs baseline: 2.4990x; 1.1613x over previous
//
#include <hip/hip_runtime.h>
#include <hip/hip_bf16.h>

// h_out[v] = sum over edges (u->v) of features[u]
// Round-6: k25 redesigned around the scattered-store-transaction wall:
//  - edges loaded ONCE into registers (src+dst, nontemporal),
//  - ONE rank-returning LDS atomic per edge,
//  - scatter into LDS seg[chunk] (random LDS writes ~free),
//  - coalesced vint4 flush seg -> bdata (16 lanes/64B line vs 1).
// k7 transpose, k1 pack, k6 gather carried over unchanged.

#define NN     100000
#define FD     5
#define NOUTT  (NN * FD)      // 500000
#define NPS    32             // nodes per bucket
#define NPS_SH 5
#define NB     3125           // 100000 / 32 exactly
#define NBP1   3126           // pscan row length (sentinel row[NB] = chunk)
#define NSB    512            // chunks (chunk = 12500 edges)
#define BLK    256
#define BLK25  1024           // k25 block
#define K25VPT 4              // 4*1024 = 4096 >= 3125
#define CAPE   12800          // max chunk held in LDS seg (50KB + h 12.5KB)
#define NXCD   8

typedef int vint4 __attribute__((ext_vector_type(4)));

__device__ inline unsigned bf16rtn(float x) {          // fp32 -> bf16 (RTN)
    unsigned u = __float_as_uint(x);
    u += 0x7fffu + ((u >> 16) & 1u);
    return u >> 16;
}
__device__ inline float lo16(unsigned v) { return __uint_as_float(v << 16); }
__device__ inline float hi16(unsigned v) { return __uint_as_float(v & 0xffff0000u); }

// XCD-contiguous chunk assignment (512 = 8*64 exact).
__device__ inline int chunk_of_block(int bid) {
    return (bid & (NXCD - 1)) * (NSB / NXCD) + (bid >> 3);
}
// Bijective consecutive-buckets -> same-XCD mapping for k6 (3125 = 8*390+5).
__device__ inline int bucket_of_block(int bid) {
    int xcd = bid & 7, idx = bid >> 3;
    int q = NB >> 3, r = NB & 7;                       // 390, 5
    return (xcd < r) ? xcd * (q + 1) + idx
                     : r * (q + 1) + (xcd - r) * q + idx;
}

// ---------- K25: fully in-LDS per-chunk counting sort -----------------------
// Pass A: load dst+src once -> registers; rank-returning hist atomic (the
// ONLY atomic). Scan: shfl wave-scan, 1 barrier. Pass B: scatter packed word
// into LDS seg at local position (random LDS write ~free). Flush: coalesced
// vint4 stores seg -> this chunk's private bdata window (full 64B lines).
__global__ __launch_bounds__(BLK25) void k25_sortchunk(
        const int* __restrict__ src, const int* __restrict__ dst,
        unsigned short* __restrict__ bh, int* __restrict__ bdata, int chunk) {
    __shared__ int h[NB];         // counts -> then LOCAL exclusive bases
    __shared__ int seg[CAPE];     // chunk sorted by bucket (50 KB)
    __shared__ int wv[16];
    int t = threadIdx.x;
    for (int b = t; b < NB; b += BLK25) h[b] = 0;
    __syncthreads();
    int cblk = chunk_of_block(blockIdx.x);
    long long e0 = (long long)cblk * chunk;
    const vint4* d4 = (const vint4*)(dst + e0);
    const vint4* s4 = (const vint4*)(src + e0);
    int n4 = chunk >> 2;          // <= 3200 (gate) -> <= 4 iters/thread

    // Pass A: load once, keep (bucket, packed word) in registers (static idx).
    int bk0[4], bk1[4], bk2[4], bk3[4];   // buckets, iter 0..3
    int wd0[4], wd1[4], wd2[4], wd3[4];   // packed words
    int rk0[4], rk1[4], rk2[4], rk3[4];   // ranks
    bool a0v, a1v, a2v, a3v;
#define LOADIT(IT, BK, WD)                                             \
    {                                                                  \
        int i = t + IT * BLK25;                                        \
        if (i < n4) {                                                  \
            vint4 d = __builtin_nontemporal_load(&d4[i]);              \
            vint4 s = __builtin_nontemporal_load(&s4[i]);              \
            BK[0] = d[0] >> NPS_SH; WD[0] = (s[0] << NPS_SH) | (d[0] & (NPS - 1)); \
            BK[1] = d[1] >> NPS_SH; WD[1] = (s[1] << NPS_SH) | (d[1] & (NPS - 1)); \
            BK[2] = d[2] >> NPS_SH; WD[2] = (s[2] << NPS_SH) | (d[2] & (NPS - 1)); \
            BK[3] = d[3] >> NPS_SH; WD[3] = (s[3] << NPS_SH) | (d[3] & (NPS - 1)); \
        }                                                              \
    }
    a0v = (t < n4);               LOADIT(0, bk0, wd0)
    a1v = (t + BLK25 < n4);       LOADIT(1, bk1, wd1)
    a2v = (t + 2 * BLK25 < n4);   LOADIT(2, bk2, wd2)
    a3v = (t + 3 * BLK25 < n4);   LOADIT(3, bk3, wd3)
#undef LOADIT
#define RANKIT(AV, BK, RK)                                             \
    if (AV) {                                                          \
        RK[0] = atomicAdd(&h[BK[0]], 1);                               \
        RK[1] = atomicAdd(&h[BK[1]], 1);                               \
        RK[2] = atomicAdd(&h[BK[2]], 1);                               \
        RK[3] = atomicAdd(&h[BK[3]], 1);                               \
    }
    RANKIT(a0v, bk0, rk0)
    RANKIT(a1v, bk1, rk1)
    RANKIT(a2v, bk2, rk2)
    RANKIT(a3v, bk3, rk3)
#undef RANKIT
    __syncthreads();

    // Shfl-based exclusive scan of the NB counts.
    int v[K25VPT], sum = 0;
#pragma unroll
    for (int k = 0; k < K25VPT; ++k) {
        int j = K25VPT * t + k;
        v[k] = (j < NB) ? h[j] : 0;
        sum += v[k];
    }
    int lane = t & 63, wid = t >> 6;
    int sc = sum;
#pragma unroll
    for (int off = 1; off < 64; off <<= 1) {
        int u = __shfl_up(sc, off, 64);
        if (lane >= off) sc += u;
    }
    if (lane == 63) wv[wid] = sc;
    __syncthreads();
    int woff = 0;
#pragma unroll
    for (int w2 = 0; w2 < 16; ++w2) woff += (w2 < wid) ? wv[w2] : 0;
    int run = woff + sc - sum;    // LOCAL exclusive prefix for j = 4t
    unsigned short* row = bh + (size_t)cblk * NBP1;
#pragma unroll
    for (int k = 0; k < K25VPT; ++k) {
        int j = K25VPT * t + k;
        if (j < NB) { row[j] = (unsigned short)run; h[j] = run; }
        run += v[k];
    }
    if (t == 0) row[NB] = (unsigned short)chunk;
    __syncthreads();

    // Pass B: scatter into LDS seg (random LDS writes, ~2-way = free).
#define SCAT(AV, BK, WD, RK)                                           \
    if (AV) {                                                          \
        seg[h[BK[0]] + RK[0]] = WD[0];                                 \
        seg[h[BK[1]] + RK[1]] = WD[1];                                 \
        seg[h[BK[2]] + RK[2]] = WD[2];                                 \
        seg[h[BK[3]] + RK[3]] = WD[3];                                 \
    }
    SCAT(a0v, bk0, wd0, rk0)
    SCAT(a1v, bk1, wd1, rk1)
    SCAT(a2v, bk2, wd2, rk2)
    SCAT(a3v, bk3, wd3, rk3)
#undef SCAT
    __syncthreads();

    // Flush: coalesced vint4 stores into the chunk's private bdata window.
    vint4* out4 = (vint4*)(bdata + (size_t)cblk * chunk);
    const vint4* s4l = (const vint4*)seg;
    for (int i = t; i < n4; i += BLK25) out4[i] = s4l[i];
}

// ---------- K7: transpose bh [chunk][bucket] -> bhT [bucket][chunk] --------
#define TD 64
__global__ __launch_bounds__(256) void k7_transpose(const unsigned short* __restrict__ bh,
                                                    unsigned short* __restrict__ bhT) {
    __shared__ unsigned short tile[TD][TD + 1];
    int jx = blockIdx.x * TD;      // bucket-dim tile origin
    int cy = blockIdx.y * TD;      // chunk-dim tile origin
    int tx = threadIdx.x & (TD - 1);
    int ty = threadIdx.x >> 6;     // 0..3
#pragma unroll
    for (int r = 0; r < 16; ++r) {
        int c = cy + ty + 4 * r;
        int j = jx + tx;
        tile[ty + 4 * r][tx] =
            (j < NBP1) ? bh[(size_t)c * NBP1 + j] : (unsigned short)0;
    }
    __syncthreads();
#pragma unroll
    for (int r = 0; r < 16; ++r) {
        int j = jx + ty + 4 * r;
        int c = cy + tx;
        if (j < NBP1) bhT[(size_t)j * NSB + c] = tile[tx][ty + 4 * r];
    }
}

// ---------- K1: bf16-pack rows 5 f32 -> 16 B --------------------------------
__global__ __launch_bounds__(BLK) void k1_pad(const float* __restrict__ f,
                                              uint4* __restrict__ fp) {
    int i = blockIdx.x * BLK + threadIdx.x;
    if (i < NN) {
        const float* r = f + (long long)i * FD;
        unsigned w0 = bf16rtn(r[0]), w1 = bf16rtn(r[1]), w2 = bf16rtn(r[2]);
        unsigned w3 = bf16rtn(r[3]), w4 = bf16rtn(r[4]);
        uint4 o;
        o.x = w0 | (w1 << 16);
        o.y = w2 | (w3 << 16);
        o.z = w4;
        o.w = 0u;
        fp[i] = o;
    }
}

// ---------- K6: one block per bucket (unchanged) ----------------------------
#define CAP 3072              // window capacity (bucket mean 2048, max ~2.3K)
#define WPT (CAP / BLK)       // 12
__global__ __launch_bounds__(BLK) void k6_gather(const int* __restrict__ bdata,
                                                 const uint4* __restrict__ fp,
                                                 const unsigned short* __restrict__ bhT,
                                                 float* __restrict__ out, int chunk) {
    __shared__ int seg[CAP];          // entries sorted by local node (12 KB)
    __shared__ int cum[NSB + 1];      // global exclusive position per chunk
    __shared__ int gst[NSB];          // bdata index of each chunk's sub-range
    __shared__ int hist[NPS];
    __shared__ int sbase[NPS];
    __shared__ int wsum[BLK / 64];
    int t = threadIdx.x;
    int b = bucket_of_block(blockIdx.x);

    // Phase 0: coalesced (start,len) for chunks 2t,2t+1 from bhT rows b,b+1.
    const unsigned* r0 = (const unsigned*)(bhT + (size_t)b * NSB);
    const unsigned* r1 = (const unsigned*)(bhT + (size_t)(b + 1) * NSB);
    unsigned s0 = r0[t], s1 = r1[t];
    int st0 = (int)(s0 & 0xffffu), st1 = (int)(s0 >> 16);
    int l0 = (int)(s1 & 0xffffu) - st0;
    int l1 = (int)(s1 >> 16) - st1;
    int pair = l0 + l1;
    // wave-inclusive scan of pair (shfl; no barriers)
    int lane = t & 63, wid = t >> 6;
    int sc = pair;
#pragma unroll
    for (int off = 1; off < 64; off <<= 1) {
        int u = __shfl_up(sc, off, 64);
        if (lane >= off) sc += u;
    }
    if (lane == 63) wsum[wid] = sc;
    __syncthreads();
    int w0s = wsum[0], w1s = wsum[1], w2s = wsum[2], w3s = wsum[3];
    int woff = (wid > 0 ? w0s : 0) + (wid > 1 ? w1s : 0) + (wid > 2 ? w2s : 0);
    int n = w0s + w1s + w2s + w3s;            // bucket total
    int exc = woff + sc - pair;               // global rank of chunk 2t start
    cum[2 * t]     = exc;
    cum[2 * t + 1] = exc + l0;
    gst[2 * t]     = 2 * t * chunk + st0;
    gst[2 * t + 1] = (2 * t + 1) * chunk + st1;
    if (t == 0) cum[NSB] = n;
    // (first in-loop barrier publishes cum/gst)

    int grp = t >> 3;             // node 0..31 this 8-thread team owns
    int sub = t & 7;
    float a0 = 0.f, a1 = 0.f, a2 = 0.f, a3 = 0.f, a4 = 0.f;

    for (int ws = 0; ws < n; ws += CAP) {
        int we = ws + CAP; if (we > n) we = n;
        int m = we - ws;
        if (t < NPS) hist[t] = 0;
        __syncthreads();

        // Balanced register gather: position -> (chunk via binary search) ->
        // direct bdata load. 12 independent searches/loads per thread (ILP).
        int w[WPT], rk[WPT];
#pragma unroll
        for (int k = 0; k < WPT; ++k) {
            int idx = t + k * BLK;
            w[k] = -1;
            if (idx < m) {
                int p = ws + idx;
                int lo = 0;
#pragma unroll
                for (int stp = 256; stp > 0; stp >>= 1) {
                    int mid = lo + stp;                 // <= 512 always
                    lo = (cum[mid] <= p) ? mid : lo;
                }
                w[k] = bdata[gst[lo] + (p - cum[lo])];
            }
        }
        // Rank pass (the ONLY atomic): w >= 0 always for real entries.
#pragma unroll
        for (int k = 0; k < WPT; ++k)
            rk[k] = (w[k] >= 0) ? atomicAdd(&hist[w[k] & (NPS - 1)], 1) : 0;
        __syncthreads();

        // Exclusive scan of 32 counts (wave 0, lanes 0..31).
        if (t < NPS) {
            int v = hist[t];
            int scn = v;
#pragma unroll
            for (int off = 1; off < NPS; off <<= 1) {
                int u = __shfl_up(scn, off, 64);
                if (t >= off) scn += u;
            }
            sbase[t] = scn - v;
        }
        __syncthreads();

        // Scatter u into node-sorted position (rank known, no atomics).
#pragma unroll
        for (int k = 0; k < WPT; ++k) {
            if (w[k] >= 0)
                seg[sbase[w[k] & (NPS - 1)] + rk[k]] = w[k] >> NPS_SH;
        }
        __syncthreads();

        // Accumulate: 8 threads per node, strided slice, registers only.
        int sg0 = sbase[grp], cnt = hist[grp];
        int j = sub;
        for (; j + 24 < cnt; j += 32) {
            int u0 = seg[sg0 + j],      u1 = seg[sg0 + j + 8];
            int u2 = seg[sg0 + j + 16], u3 = seg[sg0 + j + 24];
            uint4 q0 = fp[u0], q1 = fp[u1], q2 = fp[u2], q3 = fp[u3];
            a0 += lo16(q0.x); a1 += hi16(q0.x); a2 += lo16(q0.y); a3 += hi16(q0.y); a4 += lo16(q0.z);
            a0 += lo16(q1.x); a1 += hi16(q1.x); a2 += lo16(q1.y); a3 += hi16(q1.y); a4 += lo16(q1.z);
            a0 += lo16(q2.x); a1 += hi16(q2.x); a2 += lo16(q2.y); a3 += hi16(q2.y); a4 += lo16(q2.z);
            a0 += lo16(q3.x); a1 += hi16(q3.x); a2 += lo16(q3.y); a3 += hi16(q3.y); a4 += lo16(q3.z);
        }
        for (; j < cnt; j += 8) {
            int u = seg[sg0 + j];
            uint4 q = fp[u];
            a0 += lo16(q.x); a1 += hi16(q.x); a2 += lo16(q.y); a3 += hi16(q.y); a4 += lo16(q.z);
        }
        __syncthreads();   // LDS reused next window
    }

    // Reduce the 8 partials per node within the 8-lane cluster.
    a0 += __shfl_down(a0, 4, 8); a0 += __shfl_down(a0, 2, 8); a0 += __shfl_down(a0, 1, 8);
    a1 += __shfl_down(a1, 4, 8); a1 += __shfl_down(a1, 2, 8); a1 += __shfl_down(a1, 1, 8);
    a2 += __shfl_down(a2, 4, 8); a2 += __shfl_down(a2, 2, 8); a2 += __shfl_down(a2, 1, 8);
    a3 += __shfl_down(a3, 4, 8); a3 += __shfl_down(a3, 2, 8); a3 += __shfl_down(a3, 1, 8);
    a4 += __shfl_down(a4, 4, 8); a4 += __shfl_down(a4, 2, 8); a4 += __shfl_down(a4, 1, 8);
    if (sub == 0) {
        // Exclusive owner; NB*NPS*FD == NOUTT exactly.
        float* o = out + (size_t)b * (NPS * FD) + grp * FD;
        o[0] = a0; o[1] = a1; o[2] = a2; o[3] = a3; o[4] = a4;
    }
}

// ---------- Fallback: direct global atomics ---------------------------------
__global__ void scatter_add_fallback(const float* __restrict__ features,
                                     const int* __restrict__ src,
                                     const int* __restrict__ dst,
                                     float* __restrict__ out, int n_edges) {
    int idx = blockIdx.x * blockDim.x + threadIdx.x;
    int stride = gridDim.x * blockDim.x;
    for (int e = idx; e < n_edges; e += stride) {
        int u = src[e], v = dst[e];
        const float* f = features + (long long)u * FD;
        float* o = out + (long long)v * FD;
#pragma unroll
        for (int k = 0; k < FD; ++k) atomicAdd(&o[k], f[k]);
    }
}

extern "C" void kernel_launch(void* const* d_in, const int* in_sizes, int n_in,
                              void* d_out, int out_size, void* d_ws, size_t ws_size,
                              hipStream_t stream) {
    const float* features = (const float*)d_in[0];
    const int*   src      = (const int*)d_in[1];
    const int*   dst      = (const int*)d_in[2];
    float* out = (float*)d_out;
    int n_edges = in_sizes[1];
    int chunk = n_edges / NSB;

    // ws carve: bdata | bh | bhT. fpad OVERLAPS bh (bh dead after k7; k1
    // runs after k7).
    size_t o_bd = 0;                                        // bdata: E*4
    size_t o_bh = o_bd + (size_t)n_edges * 4;               // bh:  NSB*NBP1*2
    size_t sz_bh = (size_t)NSB * NBP1 * 2;                  // 3.2MB
    size_t o_bt = o_bh + ((sz_bh + 15) & ~(size_t)15);      // bhT: NBP1*NSB*2
    size_t o_fp = o_bh;                                     // fpad: NN*16 (1.6MB <= sz_bh)
    size_t need = o_bt + ((sz_bh + 15) & ~(size_t)15);

    bool fast = (out_size == NOUTT) && (in_sizes[0] == NOUTT) &&
                (n_edges % (NSB * 4) == 0) && (chunk <= CAPE) &&
                (need <= ws_size);

    if (fast) {
        char* w = (char*)d_ws;
        int*            bdata = (int*)(w + o_bd);
        unsigned short* bh    = (unsigned short*)(w + o_bh);
        unsigned short* bhT   = (unsigned short*)(w + o_bt);
        uint4*          fpad  = (uint4*)(w + o_fp);
        dim3 g7((NBP1 + TD - 1) / TD, NSB / TD);
        k25_sortchunk<<<NSB, BLK25, 0, stream>>>(src, dst, bh, bdata, chunk);
        k7_transpose <<<g7, 256, 0, stream>>>(bh, bhT);
        k1_pad       <<<(NN + BLK - 1) / BLK, BLK, 0, stream>>>(features, fpad);
        k6_gather    <<<NB, BLK, 0, stream>>>(bdata, fpad, bhT, out, chunk);
    } else {
        (void)hipMemsetAsync(d_out, 0, (size_t)out_size * sizeof(float), stream);
        int grid = (n_edges + BLK - 1) / BLK;
        if (grid > 65535) grid = 65535;
        scatter_add_fallback<<<grid, BLK, 0, stream>>>(features, src, dst, out, n_edges);
    }
}